// Round 1
// baseline (5322.045 us; speedup 1.0000x reference)
//
#include <hip/hip_runtime.h>
#include <math.h>

#define B_ 8
#define NP_ 25600
#define T_ (B_*NP_)          // 204800 tokens
#define D_ 256
#define H_ 128
#define DD_ 128
#define NBINS_ 200
#define NIDS_ 400            // bin_idx in [0, 398]
#define PB_ 128              // bin size
#define NC_ 100              // codebook columns used
#define GT_ (B_*NBINS_)      // 1600 bins total

__device__ __forceinline__ float eluf(float v){ return v > 0.f ? v : expm1f(v); }

// ---------------- mask dtype detection & conversion ----------------
__global__ void k_mask_detect(const unsigned int* __restrict__ m, int* __restrict__ flags){
  int any_f1 = 0, any_o = 0;
  for (int i = blockIdx.x*blockDim.x + threadIdx.x; i < T_/4; i += gridDim.x*blockDim.x){
    unsigned int w = m[i];
    if (w == 0x3F800000u) any_f1 = 1;
    else if (w > 1u) any_o = 1;
  }
  if (any_f1) atomicOr(&flags[0], 1);
  if (any_o)  atomicOr(&flags[1], 1);
}

__global__ void k_mask_convert(const void* __restrict__ m, const int* __restrict__ flags,
                               float* __restrict__ mskf){
  int i = blockIdx.x*256 + threadIdx.x;
  int mode = flags[0] ? 2 : (flags[1] ? 1 : 0);  // 2=f32, 1=u8, 0=i32
  bool v;
  if (mode == 2)      v = ((const float*)m)[i] != 0.f;
  else if (mode == 1) v = ((const unsigned char*)m)[i] != 0;
  else                v = ((const int*)m)[i] != 0;
  mskf[i] = v ? 1.f : 0.f;
}

// ---------------- layernorm: one wave per token ----------------
__global__ __launch_bounds__(256) void k_ln(const float* __restrict__ x,
    const float* __restrict__ g, const float* __restrict__ b, float* __restrict__ xn){
  const int wave = threadIdx.x >> 6, lane = threadIdx.x & 63;
  const long t = (long)blockIdx.x*4 + wave;
  float4 v = ((const float4*)(x + t*D_))[lane];
  float s  = v.x + v.y + v.z + v.w;
  float s2 = v.x*v.x + v.y*v.y + v.z*v.z + v.w*v.w;
  #pragma unroll
  for (int o = 32; o; o >>= 1){ s += __shfl_xor(s, o); s2 += __shfl_xor(s2, o); }
  const float mu = s * (1.f/D_);
  float var = s2*(1.f/D_) - mu*mu;
  var = fmaxf(var, 0.f);
  const float rs = rsqrtf(var + 1e-6f);
  float4 gg = ((const float4*)g)[lane];
  float4 bb = ((const float4*)b)[lane];
  float4 o4;
  o4.x = (v.x-mu)*rs*gg.x + bb.x;
  o4.y = (v.y-mu)*rs*gg.y + bb.y;
  o4.z = (v.z-mu)*rs*gg.z + bb.z;
  o4.w = (v.w-mu)*rs*gg.w + bb.w;
  ((float4*)(xn + t*D_))[lane] = o4;
}

// ---------------- generic token GEMM: C[T,N] = epi(A[T,K] @ W[K,N]) ----------------
// 64x64 tile per block, 256 threads (16x16, 4x4 micro-tile). LDS strides 66 (2-way max).
template<int K, int N, int EPI, bool RM>
__global__ __launch_bounds__(256) void k_gemm(const float* __restrict__ A,
    const float* __restrict__ W, const float* __restrict__ bias,
    const float* __restrict__ rm, float* __restrict__ C){
  __shared__ float As[64*66];
  __shared__ float Ws[64*66];
  __shared__ float rms[64];
  const int tid = threadIdx.x;
  const long m0 = (long)blockIdx.x * 64;
  const int n0 = blockIdx.y * 64;
  const int ty = tid >> 4, tx = tid & 15;
  const int lk = tid & 63, lr = tid >> 6;
  float acc[4][4] = {};
  if (RM && tid < 64) rms[tid] = rm[m0 + tid];
  for (int kc = 0; kc < K; kc += 64){
    __syncthreads();
    #pragma unroll
    for (int l = 0; l < 16; ++l){
      float a = A[(m0 + lr + l*4)*K + kc + lk];
      if (RM) a *= rms[lr + l*4];
      As[lk*66 + lr + l*4] = a;
    }
    #pragma unroll
    for (int l = 0; l < 16; ++l)
      Ws[(lr + l*4)*66 + lk] = W[(long)(kc + lr + l*4)*N + n0 + lk];
    __syncthreads();
    #pragma unroll
    for (int k = 0; k < 64; ++k){
      const float2 a01 = *(const float2*)&As[k*66 + ty*4];
      const float2 a23 = *(const float2*)&As[k*66 + ty*4 + 2];
      const float2 b01 = *(const float2*)&Ws[k*66 + tx*4];
      const float2 b23 = *(const float2*)&Ws[k*66 + tx*4 + 2];
      const float av[4] = {a01.x, a01.y, a23.x, a23.y};
      const float bv[4] = {b01.x, b01.y, b23.x, b23.y};
      #pragma unroll
      for (int i = 0; i < 4; ++i)
        #pragma unroll
        for (int j = 0; j < 4; ++j)
          acc[i][j] = fmaf(av[i], bv[j], acc[i][j]);
    }
  }
  #pragma unroll
  for (int i = 0; i < 4; ++i){
    const long row = m0 + ty*4 + i;
    #pragma unroll
    for (int j = 0; j < 4; ++j){
      const int col = n0 + tx*4 + j;
      float v = acc[i][j];
      if (EPI == 1){ v += bias[col]; v = eluf(v); }
      C[row*N + col] = v;
    }
  }
}

// ---------------- fused gate/het GEMM + mix epilogue ----------------
// out = elu(sigmoid(Xm@Wt + bt) * fB + (1-sigmoid)*(Xm@Wh)) * rm,  Xm = X*rm
__global__ __launch_bounds__(256) void k_ghmix(const float* __restrict__ X,
    const float* __restrict__ Wt, const float* __restrict__ Wh,
    const float* __restrict__ bt, const float* __restrict__ fB,
    const float* __restrict__ rm, float* __restrict__ C){
  __shared__ float As[64*66];
  __shared__ float Ts[64*66];
  __shared__ float Hs[64*66];
  __shared__ float rms[64];
  const int tid = threadIdx.x;
  const long m0 = (long)blockIdx.x * 64;
  const int n0 = blockIdx.y * 64;
  const int ty = tid >> 4, tx = tid & 15;
  const int lk = tid & 63, lr = tid >> 6;
  float at[4][4] = {}, ah[4][4] = {};
  if (tid < 64) rms[tid] = rm[m0 + tid];
  for (int kc = 0; kc < D_; kc += 64){
    __syncthreads();
    #pragma unroll
    for (int l = 0; l < 16; ++l){
      As[lk*66 + lr + l*4] = X[(m0 + lr + l*4)*D_ + kc + lk] * rms[lr + l*4];
      Ts[(lr + l*4)*66 + lk] = Wt[(long)(kc + lr + l*4)*D_ + n0 + lk];
      Hs[(lr + l*4)*66 + lk] = Wh[(long)(kc + lr + l*4)*D_ + n0 + lk];
    }
    __syncthreads();
    #pragma unroll
    for (int k = 0; k < 64; ++k){
      const float2 a01 = *(const float2*)&As[k*66 + ty*4];
      const float2 a23 = *(const float2*)&As[k*66 + ty*4 + 2];
      const float2 t01 = *(const float2*)&Ts[k*66 + tx*4];
      const float2 t23 = *(const float2*)&Ts[k*66 + tx*4 + 2];
      const float2 h01 = *(const float2*)&Hs[k*66 + tx*4];
      const float2 h23 = *(const float2*)&Hs[k*66 + tx*4 + 2];
      const float av[4] = {a01.x, a01.y, a23.x, a23.y};
      const float tv[4] = {t01.x, t01.y, t23.x, t23.y};
      const float hv[4] = {h01.x, h01.y, h23.x, h23.y};
      #pragma unroll
      for (int i = 0; i < 4; ++i)
        #pragma unroll
        for (int j = 0; j < 4; ++j){
          at[i][j] = fmaf(av[i], tv[j], at[i][j]);
          ah[i][j] = fmaf(av[i], hv[j], ah[i][j]);
        }
    }
  }
  #pragma unroll
  for (int i = 0; i < 4; ++i){
    const long row = m0 + ty*4 + i;
    const float rv = rms[ty*4 + i];
    #pragma unroll
    for (int j = 0; j < 4; ++j){
      const int col = n0 + tx*4 + j;
      const float gt = 1.f/(1.f + expf(-(at[i][j] + bt[col])));
      const float fh = fB[row*D_ + col];
      C[row*D_ + col] = eluf(gt*fh + (1.f - gt)*ah[i][j]) * rv;
    }
  }
}

// ---------------- per-bin GEMM: out[g] = dm[g](128x128) @ t[g](128x256) ----------------
__global__ __launch_bounds__(256) void k_binmm(const float* __restrict__ dm,
    const float* __restrict__ t, float* __restrict__ out){
  __shared__ float As[64*130];  // [q][p] transposed dm tile
  __shared__ float Ws[64*66];   // [q][n]
  const int g = blockIdx.x;
  const int n0 = blockIdx.y * 64;
  const int tid = threadIdx.x;
  const int ty = tid >> 4, tx = tid & 15;
  const int lk = tid & 63, lr = tid >> 6;
  const float* dmg = dm + (long)g*PB_*PB_;
  const float* tg = t + (long)g*PB_*D_;
  float acc[8][4] = {};
  for (int kc = 0; kc < PB_; kc += 64){
    __syncthreads();
    #pragma unroll
    for (int l = 0; l < 32; ++l)
      As[lk*130 + lr + l*4] = dmg[(lr + l*4)*PB_ + kc + lk];
    #pragma unroll
    for (int l = 0; l < 16; ++l)
      Ws[(lr + l*4)*66 + lk] = tg[(kc + lr + l*4)*D_ + n0 + lk];
    __syncthreads();
    #pragma unroll
    for (int k = 0; k < 64; ++k){
      float av[8], bv[4];
      #pragma unroll
      for (int h = 0; h < 4; ++h){
        const float2 aa = *(const float2*)&As[k*130 + ty*8 + h*2];
        av[h*2] = aa.x; av[h*2+1] = aa.y;
      }
      const float2 b01 = *(const float2*)&Ws[k*66 + tx*4];
      const float2 b23 = *(const float2*)&Ws[k*66 + tx*4 + 2];
      bv[0]=b01.x; bv[1]=b01.y; bv[2]=b23.x; bv[3]=b23.y;
      #pragma unroll
      for (int i = 0; i < 8; ++i)
        #pragma unroll
        for (int j = 0; j < 4; ++j)
          acc[i][j] = fmaf(av[i], bv[j], acc[i][j]);
    }
  }
  #pragma unroll
  for (int i = 0; i < 8; ++i){
    const long row = (long)g*PB_ + ty*8 + i;
    #pragma unroll
    for (int j = 0; j < 4; ++j)
      out[row*D_ + n0 + tx*4 + j] = acc[i][j];
  }
}

// ---------------- per-bin pairwise Gaussian kernel matrix ----------------
__global__ __launch_bounds__(256) void k_dm(const float* __restrict__ xm,
    const float* __restrict__ rm, float* __restrict__ dmo){
  __shared__ float Xc[64*130];   // [d][p] transposed masked tile
  __shared__ float nsqs[128];
  __shared__ float ms[128];
  const int g = blockIdx.x;
  const int tid = threadIdx.x;
  const int ty = tid >> 4, tx = tid & 15;
  const int p0 = ty*8, q0 = tx*8;
  const int ld = tid & 63, lp = tid >> 6;
  if (tid < 128) ms[tid] = rm[g*PB_ + tid];
  float inner[8][8] = {};
  for (int dc = 0; dc < DD_; dc += 64){
    __syncthreads();
    #pragma unroll
    for (int l = 0; l < 32; ++l){
      const int p = lp + l*4;
      Xc[ld*130 + p] = xm[((long)g*PB_ + p)*DD_ + dc + ld] * ms[p];
    }
    __syncthreads();
    #pragma unroll
    for (int d = 0; d < 64; ++d){
      float a[8], b[8];
      #pragma unroll
      for (int h = 0; h < 4; ++h){
        const float2 aa = *(const float2*)&Xc[d*130 + p0 + h*2];
        const float2 bb = *(const float2*)&Xc[d*130 + q0 + h*2];
        a[h*2] = aa.x; a[h*2+1] = aa.y;
        b[h*2] = bb.x; b[h*2+1] = bb.y;
      }
      #pragma unroll
      for (int i = 0; i < 8; ++i)
        #pragma unroll
        for (int j = 0; j < 8; ++j)
          inner[i][j] = fmaf(a[i], b[j], inner[i][j]);
    }
  }
  if (ty == tx){
    #pragma unroll
    for (int i = 0; i < 8; ++i) nsqs[p0 + i] = inner[i][i];
  }
  __syncthreads();
  #pragma unroll
  for (int i = 0; i < 8; ++i){
    const int p = p0 + i;
    const float npv = nsqs[p], mp = ms[p];
    float o[8];
    #pragma unroll
    for (int j = 0; j < 8; ++j){
      const int q = q0 + j;
      float d2 = npv + nsqs[q] - 2.f*inner[i][j];
      d2 = fminf(fmaxf(d2, 1e-6f), 1e6f);
      float w = expf(-0.1f * sqrtf(d2));
      w = fminf(w, 1.f);
      o[j] = w * mp * ms[q];
    }
    float4* o4 = (float4*)&dmo[((long)g*PB_ + p)*PB_ + q0];
    o4[0] = make_float4(o[0], o[1], o[2], o[3]);
    o4[1] = make_float4(o[4], o[5], o[6], o[7]);
  }
}

// ---------------- LSH: argmax over [mul, -mul], 16 tokens per block ----------------
__global__ __launch_bounds__(256) void k_lsh(const float* __restrict__ xd,
    const float* __restrict__ cb, const float* __restrict__ mskf, int* __restrict__ bidx){
  __shared__ float cbs[DD_*NC_];
  __shared__ float rowbuf[4][DD_];
  const int tid = threadIdx.x;
  for (int i = tid; i < DD_*NC_; i += 256) cbs[i] = cb[i];
  const int wave = tid >> 6, lane = tid & 63;
  for (int tt = 0; tt < 4; ++tt){
    const long t = (long)blockIdx.x*16 + wave*4 + tt;
    __syncthreads();
    ((float2*)&rowbuf[wave][0])[lane] = ((const float2*)(xd + t*DD_))[lane];
    __syncthreads();
    float bv = -1e30f; int bi = 0;
    #pragma unroll
    for (int cc = 0; cc < 2; ++cc){
      const int c = lane + cc*64;
      if (c < NC_){
        float s = 0.f;
        #pragma unroll 8
        for (int k = 0; k < DD_; ++k) s = fmaf(rowbuf[wave][k], cbs[k*NC_ + c], s);
        if (s > bv || (s == bv && c < bi)){ bv = s; bi = c; }
        const float ns = -s; const int nc = c + NC_;
        if (ns > bv || (ns == bv && nc < bi)){ bv = ns; bi = nc; }
      }
    }
    #pragma unroll
    for (int o = 32; o; o >>= 1){
      const float ov = __shfl_xor(bv, o);
      const int oi = __shfl_xor(bi, o);
      if (ov > bv || (ov == bv && oi < bi)){ bv = ov; bi = oi; }
    }
    if (lane == 0){
      const int add = (mskf[t] != 0.f) ? 0 : (NBINS_ - 1);
      bidx[t] = bi + add;
    }
  }
}

// ---------------- counting sort (stable) ----------------
__global__ void k_hist(const int* __restrict__ bidx, int* __restrict__ hist){
  const int i = blockIdx.x*256 + threadIdx.x;
  const int b = i / NP_;
  atomicAdd(&hist[b*NIDS_ + bidx[i]], 1);
}

__global__ void k_prefix(const int* __restrict__ hist, int* __restrict__ offs){
  const int b = threadIdx.x;
  if (b < B_){
    int run = 0;
    for (int v = 0; v < NIDS_; ++v){ offs[b*NIDS_ + v] = run; run += hist[b*NIDS_ + v]; }
  }
}

__global__ __launch_bounds__(64) void k_binsort(const int* __restrict__ bidx,
    const int* __restrict__ offs, const int* __restrict__ hist, int* __restrict__ split){
  const int bv = blockIdx.x;            // b*NIDS_ + v
  if (hist[bv] == 0) return;
  const int b = bv / NIDS_, v = bv % NIDS_;
  int base = offs[bv];
  const int lane = threadIdx.x;
  const int* row = bidx + b*NP_;
  for (int i0 = 0; i0 < NP_; i0 += 64){
    const int i = i0 + lane;
    const bool m = (row[i] == v);
    const unsigned long long mk = __ballot(m);
    if (m){
      const int pos = base + __popcll(mk & ((1ull << lane) - 1ull));
      split[b*NP_ + pos] = i;
    }
    base += __popcll(mk);
  }
}

// ---------------- gather / scatter ----------------
__global__ __launch_bounds__(256) void k_gather(const float* __restrict__ xn,
    const float* __restrict__ xd, const float* __restrict__ mskf,
    const int* __restrict__ split, float* __restrict__ xb,
    float* __restrict__ xm, float* __restrict__ mskg){
  const long j = blockIdx.x;
  const int b = (int)(j / NP_);
  const int i = split[j];
  const long src = (long)b*NP_ + i;
  const int tid = threadIdx.x;
  xb[j*D_ + tid] = xn[src*D_ + tid];
  if (tid < DD_) xm[j*DD_ + tid] = xd[src*DD_ + tid];
  if (tid == 0) mskg[j] = mskf[src];
}

__global__ __launch_bounds__(256) void k_scatter(const float* __restrict__ xb,
    const int* __restrict__ split, float* __restrict__ out){
  const long j = blockIdx.x;
  const int b = (int)(j / NP_);
  const int i = split[j];
  out[((long)b*NP_ + i)*D_ + threadIdx.x] = xb[j*D_ + threadIdx.x];
}

// ---------------- driver ----------------
extern "C" void kernel_launch(void* const* d_in, const int* in_sizes, int n_in,
                              void* d_out, int out_size, void* d_ws, size_t ws_size,
                              hipStream_t stream){
  (void)in_sizes; (void)n_in; (void)out_size;
  const float* x    = (const float*)d_in[0];
  const void*  msk  = d_in[1];
  const float* ln_g = (const float*)d_in[2];
  const float* ln_b = (const float*)d_in[3];
  const float* w1 = (const float*)d_in[4];
  const float* b1 = (const float*)d_in[5];
  const float* w2 = (const float*)d_in[6];
  const float* b2 = (const float*)d_in[7];
  const float* w3 = (const float*)d_in[8];
  const float* b3 = (const float*)d_in[9];
  const float* cb = (const float*)d_in[10];
  const float* th0 = (const float*)d_in[11];
  const float* wh0 = (const float*)d_in[12];
  const float* wt0 = (const float*)d_in[13];
  const float* bt0 = (const float*)d_in[14];
  const float* th1 = (const float*)d_in[15];
  const float* wh1 = (const float*)d_in[16];
  const float* wt1 = (const float*)d_in[17];
  const float* bt1 = (const float*)d_in[18];
  float* out = (float*)d_out;

  char* ws = (char*)d_ws;
  size_t off = 0;
  auto alloc = [&](size_t bytes) -> void* {
    void* p = ws + off; off += (bytes + 255) & ~(size_t)255; return p;
  };
  int* flags = (int*)alloc(2*sizeof(int));
  int* hist  = (int*)alloc((size_t)B_*NIDS_*4);
  int* offs  = (int*)alloc((size_t)B_*NIDS_*4);
  int* bidx  = (int*)alloc((size_t)T_*4);
  int* split = (int*)alloc((size_t)T_*4);
  float* mskf = (float*)alloc((size_t)T_*4);
  float* mskg = (float*)alloc((size_t)T_*4);
  float* xb = (float*)alloc((size_t)T_*D_*4);
  float* tA = (float*)alloc((size_t)T_*D_*4);
  float* P  = (float*)alloc((size_t)T_*DD_*4);
  float* Q  = (float*)alloc((size_t)T_*DD_*4);
  if (off > ws_size) return;  // insufficient workspace: leave poison (visible failure)
  float* xn = out;            // d_out reused: xn -> f_hom -> final output

  hipMemsetAsync(flags, 0, 2*sizeof(int), stream);
  hipMemsetAsync(hist, 0, (size_t)B_*NIDS_*4, stream);

  k_mask_detect<<<64, 256, 0, stream>>>((const unsigned int*)msk, flags);
  k_mask_convert<<<T_/256, 256, 0, stream>>>(msk, flags, mskf);

  k_ln<<<T_/4, 256, 0, stream>>>(x, ln_g, ln_b, xn);

  k_gemm<D_, H_, 1, false><<<dim3(T_/64, H_/64), 256, 0, stream>>>(xn, w1, b1, nullptr, P);
  k_gemm<H_, H_, 1, false><<<dim3(T_/64, H_/64), 256, 0, stream>>>(P, w2, b2, nullptr, Q);
  k_gemm<H_, DD_, 1, false><<<dim3(T_/64, DD_/64), 256, 0, stream>>>(Q, w3, b3, nullptr, P);

  k_lsh<<<T_/16, 256, 0, stream>>>(P, cb, mskf, bidx);
  k_hist<<<T_/256, 256, 0, stream>>>(bidx, hist);
  k_prefix<<<1, 64, 0, stream>>>(hist, offs);
  k_binsort<<<B_*NIDS_, 64, 0, stream>>>(bidx, offs, hist, split);

  k_gather<<<T_, 256, 0, stream>>>(xn, P, mskf, split, xb, Q, mskg);
  k_dm<<<GT_, 256, 0, stream>>>(Q, mskg, P);

  // layer 0: xb -> tA
  k_gemm<D_, D_, 0, true><<<dim3(T_/64, D_/64), 256, 0, stream>>>(xb, th0, nullptr, mskg, tA);
  k_binmm<<<dim3(GT_, D_/64), 256, 0, stream>>>(P, tA, out);
  k_ghmix<<<dim3(T_/64, D_/64), 256, 0, stream>>>(xb, wt0, wh0, bt0, out, mskg, tA);

  // layer 1: tA -> xb
  k_gemm<D_, D_, 0, true><<<dim3(T_/64, D_/64), 256, 0, stream>>>(tA, th1, nullptr, mskg, xb);
  k_binmm<<<dim3(GT_, D_/64), 256, 0, stream>>>(P, xb, out);
  k_ghmix<<<dim3(T_/64, D_/64), 256, 0, stream>>>(tA, wt1, wh1, bt1, out, mskg, xb);

  k_scatter<<<T_, 256, 0, stream>>>(xb, split, out);
}

// Round 2
// 2556.418 us; speedup vs baseline: 2.0818x; 2.0818x over previous
//
#include <hip/hip_runtime.h>
#include <math.h>

#define B_ 8
#define NP_ 25600
#define T_ (B_*NP_)          // 204800 tokens
#define D_ 256
#define H_ 128
#define DD_ 128
#define NBINS_ 200
#define NIDS_ 400            // bin_idx in [0, 398]
#define PB_ 128              // bin size
#define NC_ 100              // codebook columns used
#define GT_ (B_*NBINS_)      // 1600 bins total

typedef __attribute__((ext_vector_type(8))) short bf16x8;
typedef __attribute__((ext_vector_type(4))) float f32x4;
typedef unsigned short u16;

__device__ __forceinline__ float eluf(float v){ return v > 0.f ? v : expm1f(v); }
__device__ __forceinline__ u16 f2bf(float f){
  union { float f; unsigned u; } v; v.f = f;
  unsigned r = v.u + 0x7fffu + ((v.u >> 16) & 1u);
  return (u16)(r >> 16);
}

// ---------------- mask dtype detection & conversion ----------------
__global__ void k_mask_detect(const unsigned int* __restrict__ m, int* __restrict__ flags){
  int any_f1 = 0, any_o = 0;
  for (int i = blockIdx.x*blockDim.x + threadIdx.x; i < T_/4; i += gridDim.x*blockDim.x){
    unsigned int w = m[i];
    if (w == 0x3F800000u) any_f1 = 1;
    else if (w > 1u) any_o = 1;
  }
  if (any_f1) atomicOr(&flags[0], 1);
  if (any_o)  atomicOr(&flags[1], 1);
}

__global__ void k_mask_convert(const void* __restrict__ m, const int* __restrict__ flags,
                               float* __restrict__ mskf){
  int i = blockIdx.x*256 + threadIdx.x;
  int mode = flags[0] ? 2 : (flags[1] ? 1 : 0);  // 2=f32, 1=u8, 0=i32
  bool v;
  if (mode == 2)      v = ((const float*)m)[i] != 0.f;
  else if (mode == 1) v = ((const unsigned char*)m)[i] != 0;
  else                v = ((const int*)m)[i] != 0;
  mskf[i] = v ? 1.f : 0.f;
}

// ---------------- layernorm: one wave per token ----------------
__global__ __launch_bounds__(256) void k_ln(const float* __restrict__ x,
    const float* __restrict__ g, const float* __restrict__ b, float* __restrict__ xn){
  const int wave = threadIdx.x >> 6, lane = threadIdx.x & 63;
  const long t = (long)blockIdx.x*4 + wave;
  float4 v = ((const float4*)(x + t*D_))[lane];
  float s  = v.x + v.y + v.z + v.w;
  float s2 = v.x*v.x + v.y*v.y + v.z*v.z + v.w*v.w;
  #pragma unroll
  for (int o = 32; o; o >>= 1){ s += __shfl_xor(s, o); s2 += __shfl_xor(s2, o); }
  const float mu = s * (1.f/D_);
  float var = s2*(1.f/D_) - mu*mu;
  var = fmaxf(var, 0.f);
  const float rs = rsqrtf(var + 1e-6f);
  float4 gg = ((const float4*)g)[lane];
  float4 bb = ((const float4*)b)[lane];
  float4 o4;
  o4.x = (v.x-mu)*rs*gg.x + bb.x;
  o4.y = (v.y-mu)*rs*gg.y + bb.y;
  o4.z = (v.z-mu)*rs*gg.z + bb.z;
  o4.w = (v.w-mu)*rs*gg.w + bb.w;
  ((float4*)(xn + t*D_))[lane] = o4;
}

// ---------------- fp32 token GEMM (FFN only; kept exact) ----------------
template<int K, int N, int EPI>
__global__ __launch_bounds__(256) void k_gemm(const float* __restrict__ A,
    const float* __restrict__ W, const float* __restrict__ bias, float* __restrict__ C){
  __shared__ float As[64*66];
  __shared__ float Ws[64*66];
  const int tid = threadIdx.x;
  const long m0 = (long)blockIdx.x * 64;
  const int n0 = blockIdx.y * 64;
  const int ty = tid >> 4, tx = tid & 15;
  const int lk = tid & 63, lr = tid >> 6;
  float acc[4][4] = {};
  for (int kc = 0; kc < K; kc += 64){
    __syncthreads();
    #pragma unroll
    for (int l = 0; l < 16; ++l)
      As[lk*66 + lr + l*4] = A[(m0 + lr + l*4)*K + kc + lk];
    #pragma unroll
    for (int l = 0; l < 16; ++l)
      Ws[(lr + l*4)*66 + lk] = W[(long)(kc + lr + l*4)*N + n0 + lk];
    __syncthreads();
    #pragma unroll
    for (int k = 0; k < 64; ++k){
      const float2 a01 = *(const float2*)&As[k*66 + ty*4];
      const float2 a23 = *(const float2*)&As[k*66 + ty*4 + 2];
      const float2 b01 = *(const float2*)&Ws[k*66 + tx*4];
      const float2 b23 = *(const float2*)&Ws[k*66 + tx*4 + 2];
      const float av[4] = {a01.x, a01.y, a23.x, a23.y};
      const float bv[4] = {b01.x, b01.y, b23.x, b23.y};
      #pragma unroll
      for (int i = 0; i < 4; ++i)
        #pragma unroll
        for (int j = 0; j < 4; ++j)
          acc[i][j] = fmaf(av[i], bv[j], acc[i][j]);
    }
  }
  #pragma unroll
  for (int i = 0; i < 4; ++i){
    const long row = m0 + ty*4 + i;
    #pragma unroll
    for (int j = 0; j < 4; ++j){
      const int col = n0 + tx*4 + j;
      float v = acc[i][j];
      if (EPI == 1){ v += bias[col]; v = eluf(v); }
      C[row*N + col] = v;
    }
  }
}

// ---------------- LSH: argmax over [mul, -mul] (exact fp32) ----------------
__global__ __launch_bounds__(256) void k_lsh(const float* __restrict__ xd,
    const float* __restrict__ cb, const float* __restrict__ mskf, int* __restrict__ bidx){
  __shared__ float cbs[DD_*NC_];
  __shared__ float rowbuf[4][DD_];
  const int tid = threadIdx.x;
  for (int i = tid; i < DD_*NC_; i += 256) cbs[i] = cb[i];
  const int wave = tid >> 6, lane = tid & 63;
  for (int tt = 0; tt < 4; ++tt){
    const long t = (long)blockIdx.x*16 + wave*4 + tt;
    __syncthreads();
    ((float2*)&rowbuf[wave][0])[lane] = ((const float2*)(xd + t*DD_))[lane];
    __syncthreads();
    float bv = -1e30f; int bi = 0;
    #pragma unroll
    for (int cc = 0; cc < 2; ++cc){
      const int c = lane + cc*64;
      if (c < NC_){
        float s = 0.f;
        #pragma unroll 8
        for (int k = 0; k < DD_; ++k) s = fmaf(rowbuf[wave][k], cbs[k*NC_ + c], s);
        if (s > bv || (s == bv && c < bi)){ bv = s; bi = c; }
        const float ns = -s; const int nc = c + NC_;
        if (ns > bv || (ns == bv && nc < bi)){ bv = ns; bi = nc; }
      }
    }
    #pragma unroll
    for (int o = 32; o; o >>= 1){
      const float ov = __shfl_xor(bv, o);
      const int oi = __shfl_xor(bi, o);
      if (ov > bv || (ov == bv && oi < bi)){ bv = ov; bi = oi; }
    }
    if (lane == 0){
      const int add = (mskf[t] != 0.f) ? 0 : (NBINS_ - 1);
      bidx[t] = bi + add;
    }
  }
}

// ---------------- counting sort (stable) ----------------
__global__ void k_hist(const int* __restrict__ bidx, int* __restrict__ hist){
  const int i = blockIdx.x*256 + threadIdx.x;
  const int b = i / NP_;
  atomicAdd(&hist[b*NIDS_ + bidx[i]], 1);
}

__global__ void k_prefix(const int* __restrict__ hist, int* __restrict__ offs){
  const int b = threadIdx.x;
  if (b < B_){
    int run = 0;
    for (int v = 0; v < NIDS_; ++v){ offs[b*NIDS_ + v] = run; run += hist[b*NIDS_ + v]; }
  }
}

__global__ __launch_bounds__(64) void k_binsort(const int* __restrict__ bidx,
    const int* __restrict__ offs, const int* __restrict__ hist, int* __restrict__ split){
  const int bv = blockIdx.x;            // b*NIDS_ + v
  if (hist[bv] == 0) return;
  const int b = bv / NIDS_, v = bv % NIDS_;
  int base = offs[bv];
  const int lane = threadIdx.x;
  const int* row = bidx + b*NP_;
  for (int i0 = 0; i0 < NP_; i0 += 64){
    const int i = i0 + lane;
    const bool m = (row[i] == v);
    const unsigned long long mk = __ballot(m);
    if (m){
      const int pos = base + __popcll(mk & ((1ull << lane) - 1ull));
      split[b*NP_ + pos] = i;
    }
    base += __popcll(mk);
  }
}

// ---------------- gather (fp32 -> masked bf16) / scatter ----------------
__global__ __launch_bounds__(256) void k_gather(const float* __restrict__ xn,
    const float* __restrict__ xd, const float* __restrict__ mskf,
    const int* __restrict__ split, u16* __restrict__ xmh,
    u16* __restrict__ xkh, float* __restrict__ mskg){
  const long j = blockIdx.x;
  const int b = (int)(j / NP_);
  const int i = split[j];
  const long src = (long)b*NP_ + i;
  const int tid = threadIdx.x;
  const float mv = mskf[src];
  xmh[j*D_ + tid] = f2bf(xn[src*D_ + tid] * mv);
  if (tid < DD_) xkh[j*DD_ + tid] = f2bf(xd[src*DD_ + tid] * mv);
  if (tid == 0) mskg[j] = mv;
}

__global__ __launch_bounds__(256) void k_scatter(const float* __restrict__ xb,
    const int* __restrict__ split, float* __restrict__ out){
  const long j = blockIdx.x;
  const int b = (int)(j / NP_);
  const int i = split[j];
  out[((long)b*NP_ + i)*D_ + threadIdx.x] = xb[j*D_ + threadIdx.x];
}

// ---------------- weight transpose+convert: o[n][k] = bf16(W[k][n]) ----------------
__global__ __launch_bounds__(256) void k_wt(const float* __restrict__ W, u16* __restrict__ o){
  const int n = blockIdx.x, k = threadIdx.x;
  o[n*D_ + k] = f2bf(W[k*D_ + n]);
}

// ---------------- MFMA helpers ----------------
// LDS layout: [rows][cols] bf16, linear, XOR-swizzle at 8-elem granularity:
// physical col8 = logical col8 ^ (row & 7). Conflict-free b128 reads/writes.
__device__ __forceinline__ void stage64(const u16* __restrict__ g, size_t row0,
    int ld, int k0, u16* Ls, int tid){
  #pragma unroll
  for (int s = 0; s < 4; ++s){
    const int r = (tid >> 3) + s*32, c8 = tid & 7;
    bf16x8 v = *(const bf16x8*)&g[(row0 + r)*(size_t)ld + k0 + c8*8];
    *(bf16x8*)&Ls[(r*8 + (c8 ^ (r & 7)))*8] = v;
  }
}
__device__ __forceinline__ void stage128(const u16* __restrict__ g, size_t row0,
    int ld, u16* Ls, int tid){
  #pragma unroll
  for (int s = 0; s < 8; ++s){
    const int r = (tid >> 4) + s*16, c8 = tid & 15;
    bf16x8 v = *(const bf16x8*)&g[(row0 + r)*(size_t)ld + c8*8];
    *(bf16x8*)&Ls[(r*16 + (c8 ^ (r & 7)))*8] = v;
  }
}
__device__ __forceinline__ bf16x8 ldf(const u16* Ls, int row, int c8, int ldc8){
  return *(const bf16x8*)&Ls[(row*ldc8 + (c8 ^ (row & 7)))*8];
}

// ---------------- tT[g][n][p] = sum_k thT[n][k] * X[g*128+p][k] ----------------
// (theta GEMM computed transposed so binmm's B operand is ready-made)
__global__ __launch_bounds__(256) void k_tmm(const u16* __restrict__ thT,
    const u16* __restrict__ X, u16* __restrict__ tT){
  __shared__ __align__(16) u16 As[128*64];
  __shared__ __align__(16) u16 Bs[128*64];
  const int g = blockIdx.x, h = blockIdx.y;
  const int tid = threadIdx.x, l = tid & 63, wid = tid >> 6;
  const int wr = wid >> 1, wc = wid & 1, lm = l & 15, lk = l >> 4;
  f32x4 acc[4][4] = {};
  for (int kt = 0; kt < 4; ++kt){
    if (kt) __syncthreads();
    stage64(thT, (size_t)h*128, D_, kt*64, As, tid);
    stage64(X,   (size_t)g*128, D_, kt*64, Bs, tid);
    __syncthreads();
    #pragma unroll
    for (int ks = 0; ks < 2; ++ks){
      bf16x8 a[4], b[4];
      #pragma unroll
      for (int mi = 0; mi < 4; ++mi) a[mi] = ldf(As, wr*64 + mi*16 + lm, ks*4 + lk, 8);
      #pragma unroll
      for (int ni = 0; ni < 4; ++ni) b[ni] = ldf(Bs, wc*64 + ni*16 + lm, ks*4 + lk, 8);
      #pragma unroll
      for (int mi = 0; mi < 4; ++mi)
        #pragma unroll
        for (int ni = 0; ni < 4; ++ni)
          acc[mi][ni] = __builtin_amdgcn_mfma_f32_16x16x32_bf16(a[mi], b[ni], acc[mi][ni], 0, 0, 0);
    }
  }
  #pragma unroll
  for (int mi = 0; mi < 4; ++mi)
    #pragma unroll
    for (int ni = 0; ni < 4; ++ni)
      #pragma unroll
      for (int r = 0; r < 4; ++r){
        const int row = wr*64 + mi*16 + lk*4 + r;   // n within half
        const int col = wc*64 + ni*16 + lm;         // p
        tT[((size_t)g*D_ + h*128 + row)*PB_ + col] = f2bf(acc[mi][ni][r]);
      }
}

// ---------------- fhom[g*128+p][h*128+n] = sum_q dm[g][p][q] * tT[g][h*128+n][q] ----------------
__global__ __launch_bounds__(256) void k_binmm(const u16* __restrict__ dmb,
    const u16* __restrict__ tT, float* __restrict__ fh){
  __shared__ __align__(16) u16 As[128*128];
  __shared__ __align__(16) u16 Bs[128*128];
  const int g = blockIdx.x, h = blockIdx.y;
  const int tid = threadIdx.x, l = tid & 63, wid = tid >> 6;
  const int wr = wid >> 1, wc = wid & 1, lm = l & 15, lk = l >> 4;
  stage128(dmb, (size_t)g*128, PB_, As, tid);
  stage128(tT, (size_t)g*D_ + h*128, PB_, Bs, tid);
  __syncthreads();
  f32x4 acc[4][4] = {};
  #pragma unroll
  for (int ks = 0; ks < 4; ++ks){
    bf16x8 a[4], b[4];
    #pragma unroll
    for (int mi = 0; mi < 4; ++mi) a[mi] = ldf(As, wr*64 + mi*16 + lm, ks*4 + lk, 16);
    #pragma unroll
    for (int ni = 0; ni < 4; ++ni) b[ni] = ldf(Bs, wc*64 + ni*16 + lm, ks*4 + lk, 16);
    #pragma unroll
    for (int mi = 0; mi < 4; ++mi)
      #pragma unroll
      for (int ni = 0; ni < 4; ++ni)
        acc[mi][ni] = __builtin_amdgcn_mfma_f32_16x16x32_bf16(a[mi], b[ni], acc[mi][ni], 0, 0, 0);
  }
  #pragma unroll
  for (int mi = 0; mi < 4; ++mi)
    #pragma unroll
    for (int ni = 0; ni < 4; ++ni)
      #pragma unroll
      for (int r = 0; r < 4; ++r){
        const int row = wr*64 + mi*16 + lk*4 + r;   // p
        const int col = wc*64 + ni*16 + lm;         // n within half
        fh[((size_t)g*PB_ + row)*D_ + h*128 + col] = acc[mi][ni][r];
      }
}

// ---------------- per-bin Gram + Gaussian kernel matrix (MFMA) ----------------
__global__ __launch_bounds__(256) void k_dm(const u16* __restrict__ xk,
    const float* __restrict__ rm, u16* __restrict__ dmb){
  __shared__ __align__(16) u16 Xs[128*128];
  __shared__ float nsq[128];
  __shared__ float msl[128];
  const int g = blockIdx.x;
  const int tid = threadIdx.x, l = tid & 63, wid = tid >> 6;
  const int wr = wid >> 1, wc = wid & 1, lm = l & 15, lk = l >> 4;
  stage128(xk, (size_t)g*128, DD_, Xs, tid);
  if (tid < 128) msl[tid] = rm[(size_t)g*128 + tid];
  __syncthreads();
  f32x4 acc[4][4] = {};
  #pragma unroll
  for (int ks = 0; ks < 4; ++ks){
    bf16x8 a[4], b[4];
    #pragma unroll
    for (int mi = 0; mi < 4; ++mi) a[mi] = ldf(Xs, wr*64 + mi*16 + lm, ks*4 + lk, 16);
    #pragma unroll
    for (int ni = 0; ni < 4; ++ni) b[ni] = ldf(Xs, wc*64 + ni*16 + lm, ks*4 + lk, 16);
    #pragma unroll
    for (int mi = 0; mi < 4; ++mi)
      #pragma unroll
      for (int ni = 0; ni < 4; ++ni)
        acc[mi][ni] = __builtin_amdgcn_mfma_f32_16x16x32_bf16(a[mi], b[ni], acc[mi][ni], 0, 0, 0);
  }
  // extract diagonal (row==col): needs wr==wc, mi==ni, (l&15)>>2 == lk
  if (wr == wc && ((lm >> 2) == lk)){
    #pragma unroll
    for (int mi = 0; mi < 4; ++mi)
      nsq[wr*64 + mi*16 + lm] = acc[mi][mi][lm & 3];
  }
  __syncthreads();
  #pragma unroll
  for (int mi = 0; mi < 4; ++mi)
    #pragma unroll
    for (int ni = 0; ni < 4; ++ni)
      #pragma unroll
      for (int r = 0; r < 4; ++r){
        const int row = wr*64 + mi*16 + lk*4 + r;
        const int col = wc*64 + ni*16 + lm;
        float d2 = nsq[row] + nsq[col] - 2.f*acc[mi][ni][r];
        d2 = fminf(fmaxf(d2, 1e-6f), 1e6f);
        float w = expf(-0.1f * sqrtf(d2));
        w = fminf(w, 1.f);
        dmb[((size_t)g*PB_ + row)*PB_ + col] = f2bf(w * msl[row] * msl[col]);
      }
}

// ---------------- fused gate/het MFMA GEMM + mix epilogue ----------------
template<int W16, int W32>
__global__ __launch_bounds__(256) void k_ghmix(const u16* __restrict__ X,
    const u16* __restrict__ Wt, const u16* __restrict__ Wh,
    const float* __restrict__ bt, const float* __restrict__ fB,
    u16* __restrict__ o16, float* __restrict__ o32){
  __shared__ __align__(16) u16 As[128*64];
  __shared__ __align__(16) u16 Ts[128*64];
  __shared__ __align__(16) u16 Hs[128*64];
  const int h = blockIdx.y;
  const size_t r0 = (size_t)blockIdx.x * 128;
  const int tid = threadIdx.x, l = tid & 63, wid = tid >> 6;
  const int wr = wid >> 1, wc = wid & 1, lm = l & 15, lk = l >> 4;
  f32x4 at[4][4] = {}, ah[4][4] = {};
  for (int kt = 0; kt < 4; ++kt){
    if (kt) __syncthreads();
    stage64(X,  r0,            D_, kt*64, As, tid);
    stage64(Wt, (size_t)h*128, D_, kt*64, Ts, tid);
    stage64(Wh, (size_t)h*128, D_, kt*64, Hs, tid);
    __syncthreads();
    #pragma unroll
    for (int ks = 0; ks < 2; ++ks){
      bf16x8 a[4], t[4], hh[4];
      #pragma unroll
      for (int mi = 0; mi < 4; ++mi) a[mi]  = ldf(As, wr*64 + mi*16 + lm, ks*4 + lk, 8);
      #pragma unroll
      for (int ni = 0; ni < 4; ++ni){
        t[ni]  = ldf(Ts, wc*64 + ni*16 + lm, ks*4 + lk, 8);
        hh[ni] = ldf(Hs, wc*64 + ni*16 + lm, ks*4 + lk, 8);
      }
      #pragma unroll
      for (int mi = 0; mi < 4; ++mi)
        #pragma unroll
        for (int ni = 0; ni < 4; ++ni){
          at[mi][ni] = __builtin_amdgcn_mfma_f32_16x16x32_bf16(a[mi], t[ni],  at[mi][ni], 0, 0, 0);
          ah[mi][ni] = __builtin_amdgcn_mfma_f32_16x16x32_bf16(a[mi], hh[ni], ah[mi][ni], 0, 0, 0);
        }
    }
  }
  #pragma unroll
  for (int mi = 0; mi < 4; ++mi)
    #pragma unroll
    for (int ni = 0; ni < 4; ++ni)
      #pragma unroll
      for (int r = 0; r < 4; ++r){
        const int row = wr*64 + mi*16 + lk*4 + r;
        const int gc  = h*128 + wc*64 + ni*16 + lm;
        const size_t gr = r0 + row;
        const float z = at[mi][ni][r] + bt[gc];
        const float gt = 1.f/(1.f + expf(-z));
        float o = gt * fB[gr*D_ + gc] + (1.f - gt) * ah[mi][ni][r];
        o = eluf(o);
        if (W16) o16[gr*D_ + gc] = f2bf(o);
        if (W32) o32[gr*D_ + gc] = o;
      }
}

// ---------------- driver ----------------
extern "C" void kernel_launch(void* const* d_in, const int* in_sizes, int n_in,
                              void* d_out, int out_size, void* d_ws, size_t ws_size,
                              hipStream_t stream){
  (void)in_sizes; (void)n_in; (void)out_size;
  const float* x    = (const float*)d_in[0];
  const void*  msk  = d_in[1];
  const float* ln_g = (const float*)d_in[2];
  const float* ln_b = (const float*)d_in[3];
  const float* w1 = (const float*)d_in[4];
  const float* b1 = (const float*)d_in[5];
  const float* w2 = (const float*)d_in[6];
  const float* b2 = (const float*)d_in[7];
  const float* w3 = (const float*)d_in[8];
  const float* b3 = (const float*)d_in[9];
  const float* cb = (const float*)d_in[10];
  const float* th0 = (const float*)d_in[11];
  const float* wh0 = (const float*)d_in[12];
  const float* wt0 = (const float*)d_in[13];
  const float* bt0 = (const float*)d_in[14];
  const float* th1 = (const float*)d_in[15];
  const float* wh1 = (const float*)d_in[16];
  const float* wt1 = (const float*)d_in[17];
  const float* bt1 = (const float*)d_in[18];
  float* out = (float*)d_out;

  char* ws = (char*)d_ws;
  size_t off = 0;
  auto alloc = [&](size_t bytes) -> void* {
    void* p = ws + off; off += (bytes + 255) & ~(size_t)255; return p;
  };
  int* flags = (int*)alloc(2*sizeof(int));
  int* hist  = (int*)alloc((size_t)B_*NIDS_*4);
  int* offs  = (int*)alloc((size_t)B_*NIDS_*4);
  int* bidx  = (int*)alloc((size_t)T_*4);
  int* split = (int*)alloc((size_t)T_*4);
  float* mskf = (float*)alloc((size_t)T_*4);
  float* mskg = (float*)alloc((size_t)T_*4);
  u16* thT0 = (u16*)alloc((size_t)D_*D_*2);
  u16* whT0 = (u16*)alloc((size_t)D_*D_*2);
  u16* wtT0 = (u16*)alloc((size_t)D_*D_*2);
  u16* thT1 = (u16*)alloc((size_t)D_*D_*2);
  u16* whT1 = (u16*)alloc((size_t)D_*D_*2);
  u16* wtT1 = (u16*)alloc((size_t)D_*D_*2);
  // BIG0: FFN hidden/x_dist (2 x T*128 f32), later reused as fhom (T*256 f32)
  float* fhom = (float*)alloc((size_t)T_*D_*4);
  float* P = fhom;
  float* Q = fhom + (size_t)T_*DD_;
  // BIG1: xmh+xkh+dmb (exactly T*256*4 bytes), later reused as G1 (fp32 final)
  u16* xmh = (u16*)alloc((size_t)T_*D_*2);
  u16* xkh = (u16*)alloc((size_t)T_*DD_*2);
  u16* dmb = (u16*)alloc((size_t)T_*DD_*2);
  float* G1 = (float*)xmh;
  u16* tT  = (u16*)alloc((size_t)T_*D_*2);
  u16* xb1 = (u16*)alloc((size_t)T_*D_*2);
  if (off > ws_size) return;  // insufficient workspace: leave poison (visible failure)
  float* xn = out;            // d_out holds xn until scatter

  hipMemsetAsync(flags, 0, 2*sizeof(int), stream);
  hipMemsetAsync(hist, 0, (size_t)B_*NIDS_*4, stream);

  k_mask_detect<<<64, 256, 0, stream>>>((const unsigned int*)msk, flags);
  k_mask_convert<<<T_/256, 256, 0, stream>>>(msk, flags, mskf);

  k_ln<<<T_/4, 256, 0, stream>>>(x, ln_g, ln_b, xn);

  k_wt<<<256, 256, 0, stream>>>(th0, thT0);
  k_wt<<<256, 256, 0, stream>>>(wh0, whT0);
  k_wt<<<256, 256, 0, stream>>>(wt0, wtT0);
  k_wt<<<256, 256, 0, stream>>>(th1, thT1);
  k_wt<<<256, 256, 0, stream>>>(wh1, whT1);
  k_wt<<<256, 256, 0, stream>>>(wt1, wtT1);

  // FFN (exact fp32 -> LSH bins bit-match round 1)
  k_gemm<D_, H_, 1><<<dim3(T_/64, H_/64), 256, 0, stream>>>(xn, w1, b1, P);
  k_gemm<H_, H_, 1><<<dim3(T_/64, H_/64), 256, 0, stream>>>(P, w2, b2, Q);
  k_gemm<H_, DD_, 1><<<dim3(T_/64, DD_/64), 256, 0, stream>>>(Q, w3, b3, P);

  k_lsh<<<T_/16, 256, 0, stream>>>(P, cb, mskf, bidx);
  k_hist<<<T_/256, 256, 0, stream>>>(bidx, hist);
  k_prefix<<<1, 64, 0, stream>>>(hist, offs);
  k_binsort<<<B_*NIDS_, 64, 0, stream>>>(bidx, offs, hist, split);

  k_gather<<<T_, 256, 0, stream>>>(xn, P, mskf, split, xmh, xkh, mskg);
  k_dm<<<GT_, 256, 0, stream>>>(xkh, mskg, dmb);

  // layer 0
  k_tmm<<<dim3(GT_, 2), 256, 0, stream>>>(thT0, xmh, tT);
  k_binmm<<<dim3(GT_, 2), 256, 0, stream>>>(dmb, tT, fhom);
  k_ghmix<1, 0><<<dim3(T_/128, 2), 256, 0, stream>>>(xmh, wtT0, whT0, bt0, fhom, xb1, nullptr);

  // layer 1 (fp32 out G1 aliases xmh/xkh/dmb, all dead by then)
  k_tmm<<<dim3(GT_, 2), 256, 0, stream>>>(thT1, xb1, tT);
  k_binmm<<<dim3(GT_, 2), 256, 0, stream>>>(dmb, tT, fhom);
  k_ghmix<0, 1><<<dim3(T_/128, 2), 256, 0, stream>>>(xb1, wtT1, whT1, bt1, fhom, nullptr, G1);

  k_scatter<<<T_, 256, 0, stream>>>(G1, split, out);
}

// Round 4
// 1938.340 us; speedup vs baseline: 2.7457x; 1.3189x over previous
//
#include <hip/hip_runtime.h>
#include <math.h>

#define B_ 8
#define NP_ 25600
#define T_ (B_*NP_)          // 204800 tokens
#define D_ 256
#define H_ 128
#define DD_ 128
#define NBINS_ 200
#define NIDS_ 400            // bin_idx in [0, 398]
#define PB_ 128              // bin size
#define NC_ 100              // codebook columns used
#define GT_ (B_*NBINS_)      // 1600 bins total

typedef __attribute__((ext_vector_type(8))) short bf16x8;
typedef __attribute__((ext_vector_type(4))) float f32x4;
typedef unsigned short u16;

__device__ __forceinline__ float eluf(float v){ return v > 0.f ? v : expm1f(v); }
__device__ __forceinline__ u16 f2bf(float f){
  union { float f; unsigned u; } v; v.f = f;
  unsigned r = v.u + 0x7fffu + ((v.u >> 16) & 1u);
  return (u16)(r >> 16);
}
__device__ __forceinline__ float bf2f(u16 h){
  union { unsigned u; float f; } v; v.u = ((unsigned)h) << 16; return v.f;
}

// ---------------- mask dtype detection & conversion ----------------
__global__ void k_mask_detect(const unsigned int* __restrict__ m, int* __restrict__ flags){
  int any_f1 = 0, any_o = 0;
  for (int i = blockIdx.x*blockDim.x + threadIdx.x; i < T_/4; i += gridDim.x*blockDim.x){
    unsigned int w = m[i];
    if (w == 0x3F800000u) any_f1 = 1;
    else if (w > 1u) any_o = 1;
  }
  if (any_f1) atomicOr(&flags[0], 1);
  if (any_o)  atomicOr(&flags[1], 1);
}

__global__ void k_mask_convert(const void* __restrict__ m, const int* __restrict__ flags,
                               float* __restrict__ mskf){
  int i = blockIdx.x*256 + threadIdx.x;
  int mode = flags[0] ? 2 : (flags[1] ? 1 : 0);  // 2=f32, 1=u8, 0=i32
  bool v;
  if (mode == 2)      v = ((const float*)m)[i] != 0.f;
  else if (mode == 1) v = ((const unsigned char*)m)[i] != 0;
  else                v = ((const int*)m)[i] != 0;
  mskf[i] = v ? 1.f : 0.f;
}

// ---------------- layernorm: one wave per token ----------------
__global__ __launch_bounds__(256) void k_ln(const float* __restrict__ x,
    const float* __restrict__ g, const float* __restrict__ b, float* __restrict__ xn){
  const int wave = threadIdx.x >> 6, lane = threadIdx.x & 63;
  const long t = (long)blockIdx.x*4 + wave;
  float4 v = ((const float4*)(x + t*D_))[lane];
  float s  = v.x + v.y + v.z + v.w;
  float s2 = v.x*v.x + v.y*v.y + v.z*v.z + v.w*v.w;
  #pragma unroll
  for (int o = 32; o; o >>= 1){ s += __shfl_xor(s, o); s2 += __shfl_xor(s2, o); }
  const float mu = s * (1.f/D_);
  float var = s2*(1.f/D_) - mu*mu;
  var = fmaxf(var, 0.f);
  const float rs = rsqrtf(var + 1e-6f);
  float4 gg = ((const float4*)g)[lane];
  float4 bb = ((const float4*)b)[lane];
  float4 o4;
  o4.x = (v.x-mu)*rs*gg.x + bb.x;
  o4.y = (v.y-mu)*rs*gg.y + bb.y;
  o4.z = (v.z-mu)*rs*gg.z + bb.z;
  o4.w = (v.w-mu)*rs*gg.w + bb.w;
  ((float4*)(xn + t*D_))[lane] = o4;
}

// ---------------- fp32 token GEMM (FFN only; bit-identical to round 2) ----------------
template<int K, int N, int EPI>
__global__ __launch_bounds__(256) void k_gemm(const float* __restrict__ A,
    const float* __restrict__ W, const float* __restrict__ bias, float* __restrict__ C){
  __shared__ float As[64*66];
  __shared__ float Ws[64*66];
  const int tid = threadIdx.x;
  const long m0 = (long)blockIdx.x * 64;
  const int n0 = blockIdx.y * 64;
  const int ty = tid >> 4, tx = tid & 15;
  const int lk = tid & 63, lr = tid >> 6;
  float acc[4][4] = {};
  for (int kc = 0; kc < K; kc += 64){
    __syncthreads();
    #pragma unroll
    for (int l = 0; l < 16; ++l)
      As[lk*66 + lr + l*4] = A[(m0 + lr + l*4)*K + kc + lk];
    #pragma unroll
    for (int l = 0; l < 16; ++l)
      Ws[(lr + l*4)*66 + lk] = W[(long)(kc + lr + l*4)*N + n0 + lk];
    __syncthreads();
    #pragma unroll
    for (int k = 0; k < 64; ++k){
      const float2 a01 = *(const float2*)&As[k*66 + ty*4];
      const float2 a23 = *(const float2*)&As[k*66 + ty*4 + 2];
      const float2 b01 = *(const float2*)&Ws[k*66 + tx*4];
      const float2 b23 = *(const float2*)&Ws[k*66 + tx*4 + 2];
      const float av[4] = {a01.x, a01.y, a23.x, a23.y};
      const float bv[4] = {b01.x, b01.y, b23.x, b23.y};
      #pragma unroll
      for (int i = 0; i < 4; ++i)
        #pragma unroll
        for (int j = 0; j < 4; ++j)
          acc[i][j] = fmaf(av[i], bv[j], acc[i][j]);
    }
  }
  #pragma unroll
  for (int i = 0; i < 4; ++i){
    const long row = m0 + ty*4 + i;
    #pragma unroll
    for (int j = 0; j < 4; ++j){
      const int col = n0 + tx*4 + j;
      float v = acc[i][j];
      if (EPI == 1){ v += bias[col]; v = eluf(v); }
      C[row*N + col] = v;
    }
  }
}

// ---------------- LSH: argmax over [mul, -mul] (exact fp32, bit-identical to round 2) ----------------
__global__ __launch_bounds__(256) void k_lsh(const float* __restrict__ xd,
    const float* __restrict__ cb, const float* __restrict__ mskf, int* __restrict__ bidx){
  __shared__ float cbs[DD_*NC_];
  __shared__ float rowbuf[4][DD_];
  const int tid = threadIdx.x;
  for (int i = tid; i < DD_*NC_; i += 256) cbs[i] = cb[i];
  const int wave = tid >> 6, lane = tid & 63;
  for (int tt = 0; tt < 4; ++tt){
    const long t = (long)blockIdx.x*16 + wave*4 + tt;
    __syncthreads();
    ((float2*)&rowbuf[wave][0])[lane] = ((const float2*)(xd + t*DD_))[lane];
    __syncthreads();
    float bv = -1e30f; int bi = 0;
    #pragma unroll
    for (int cc = 0; cc < 2; ++cc){
      const int c = lane + cc*64;
      if (c < NC_){
        float s = 0.f;
        #pragma unroll 8
        for (int k = 0; k < DD_; ++k) s = fmaf(rowbuf[wave][k], cbs[k*NC_ + c], s);
        if (s > bv || (s == bv && c < bi)){ bv = s; bi = c; }
        const float ns = -s; const int nc = c + NC_;
        if (ns > bv || (ns == bv && nc < bi)){ bv = ns; bi = nc; }
      }
    }
    #pragma unroll
    for (int o = 32; o; o >>= 1){
      const float ov = __shfl_xor(bv, o);
      const int oi = __shfl_xor(bi, o);
      if (ov > bv || (ov == bv && oi < bi)){ bv = ov; bi = oi; }
    }
    if (lane == 0){
      const int add = (mskf[t] != 0.f) ? 0 : (NBINS_ - 1);
      bidx[t] = bi + add;
    }
  }
}

// ---------------- counting sort (stable) ----------------
__global__ void k_hist(const int* __restrict__ bidx, int* __restrict__ hist){
  const int i = blockIdx.x*256 + threadIdx.x;
  const int b = i / NP_;
  atomicAdd(&hist[b*NIDS_ + bidx[i]], 1);
}

__global__ void k_prefix(const int* __restrict__ hist, int* __restrict__ offs){
  const int b = threadIdx.x;
  if (b < B_){
    int run = 0;
    for (int v = 0; v < NIDS_; ++v){ offs[b*NIDS_ + v] = run; run += hist[b*NIDS_ + v]; }
  }
}

__global__ __launch_bounds__(64) void k_binsort(const int* __restrict__ bidx,
    const int* __restrict__ offs, const int* __restrict__ hist, int* __restrict__ split){
  const int bv = blockIdx.x;            // b*NIDS_ + v
  if (hist[bv] == 0) return;
  const int b = bv / NIDS_, v = bv % NIDS_;
  int base = offs[bv];
  const int lane = threadIdx.x;
  const int* row = bidx + b*NP_;
  for (int i0 = 0; i0 < NP_; i0 += 64){
    const int i = i0 + lane;
    const bool m = (row[i] == v);
    const unsigned long long mk = __ballot(m);
    if (m){
      const int pos = base + __popcll(mk & ((1ull << lane) - 1ull));
      split[b*NP_ + pos] = i;
    }
    base += __popcll(mk);
  }
}

// ---------------- gather (fp32 -> masked bf16) ----------------
__global__ __launch_bounds__(256) void k_gather(const float* __restrict__ xn,
    const float* __restrict__ xd, const float* __restrict__ mskf,
    const int* __restrict__ split, u16* __restrict__ xmh,
    u16* __restrict__ xkh, float* __restrict__ mskg){
  const long j = blockIdx.x;
  const int b = (int)(j / NP_);
  const int i = split[j];
  const long src = (long)b*NP_ + i;
  const int tid = threadIdx.x;
  const float mv = mskf[src];
  xmh[j*D_ + tid] = f2bf(xn[src*D_ + tid] * mv);
  if (tid < DD_) xkh[j*DD_ + tid] = f2bf(xd[src*DD_ + tid] * mv);
  if (tid == 0) mskg[j] = mv;
}

// ---------------- weight prep ----------------
// bf16 transpose: o[n][k] = bf16(W[k][n]) (256x256)
__global__ __launch_bounds__(256) void k_wt(const float* __restrict__ W, u16* __restrict__ o){
  const int n = blockIdx.x, k = threadIdx.x;
  o[n*D_ + k] = f2bf(W[k*D_ + n]);
}
// combined [wt|wh] transpose: o[n][k], n<256 -> wt, else wh
__global__ __launch_bounds__(256) void k_wt2(const float* __restrict__ wt,
    const float* __restrict__ wh, u16* __restrict__ o){
  const int n = blockIdx.x, k = threadIdx.x;   // grid 512, thr 256
  const float v = (n < 256) ? wt[(size_t)k*D_ + n] : wh[(size_t)k*D_ + (n-256)];
  o[(size_t)n*D_ + k] = f2bf(v);
}

// ---------------- MFMA LDS helpers (XOR swizzle at 16B granularity) ----------------
__device__ __forceinline__ void stage64(const u16* __restrict__ g, size_t row0,
    int ld, int k0, u16* Ls, int tid){
  #pragma unroll
  for (int s = 0; s < 4; ++s){
    const int r = (tid >> 3) + s*32, c8 = tid & 7;
    bf16x8 v = *(const bf16x8*)&g[(row0 + r)*(size_t)ld + k0 + c8*8];
    *(bf16x8*)&Ls[(r*8 + (c8 ^ (r & 7)))*8] = v;
  }
}
__device__ __forceinline__ void stage128(const u16* __restrict__ g, size_t row0,
    int ld, u16* Ls, int tid){
  #pragma unroll
  for (int s = 0; s < 8; ++s){
    const int r = (tid >> 4) + s*16, c8 = tid & 15;
    bf16x8 v = *(const bf16x8*)&g[(row0 + r)*(size_t)ld + c8*8];
    *(bf16x8*)&Ls[(r*16 + (c8 ^ (r & 7)))*8] = v;
  }
}
__device__ __forceinline__ bf16x8 ldf(const u16* Ls, int row, int c8, int ldc8){
  return *(const bf16x8*)&Ls[(row*ldc8 + (c8 ^ (row & 7)))*8];
}

// ---------------- per-bin Gram + Gaussian kernel matrix (MFMA) ----------------
__global__ __launch_bounds__(256) void k_dm(const u16* __restrict__ xk,
    const float* __restrict__ rm, u16* __restrict__ dmb){
  __shared__ __align__(16) u16 Xs[128*128];
  __shared__ float nsq[128];
  __shared__ float msl[128];
  const int g = blockIdx.x;
  const int tid = threadIdx.x, l = tid & 63, wid = tid >> 6;
  const int wr = wid >> 1, wc = wid & 1, lm = l & 15, lk = l >> 4;
  stage128(xk, (size_t)g*128, DD_, Xs, tid);
  if (tid < 128) msl[tid] = rm[(size_t)g*128 + tid];
  __syncthreads();
  f32x4 acc[4][4] = {};
  #pragma unroll
  for (int ks = 0; ks < 4; ++ks){
    bf16x8 a[4], b[4];
    #pragma unroll
    for (int mi = 0; mi < 4; ++mi) a[mi] = ldf(Xs, wr*64 + mi*16 + lm, ks*4 + lk, 16);
    #pragma unroll
    for (int ni = 0; ni < 4; ++ni) b[ni] = ldf(Xs, wc*64 + ni*16 + lm, ks*4 + lk, 16);
    #pragma unroll
    for (int mi = 0; mi < 4; ++mi)
      #pragma unroll
      for (int ni = 0; ni < 4; ++ni)
        acc[mi][ni] = __builtin_amdgcn_mfma_f32_16x16x32_bf16(a[mi], b[ni], acc[mi][ni], 0, 0, 0);
  }
  if (wr == wc && ((lm >> 2) == lk)){
    #pragma unroll
    for (int mi = 0; mi < 4; ++mi)
      nsq[wr*64 + mi*16 + lm] = acc[mi][mi][lm & 3];
  }
  __syncthreads();
  #pragma unroll
  for (int mi = 0; mi < 4; ++mi)
    #pragma unroll
    for (int ni = 0; ni < 4; ++ni)
      #pragma unroll
      for (int r = 0; r < 4; ++r){
        const int row = wr*64 + mi*16 + lk*4 + r;
        const int col = wc*64 + ni*16 + lm;
        float d2 = nsq[row] + nsq[col] - 2.f*acc[mi][ni][r];
        d2 = fminf(fmaxf(d2, 1e-6f), 1e6f);
        float w = expf(-0.1f * sqrtf(d2));
        w = fminf(w, 1.f);
        dmb[((size_t)g*PB_ + row)*PB_ + col] = f2bf(w * msl[row] * msl[col]);
      }
}

// ---------------- tT[g][n][p] = sum_k thT[n][k] * X[g*128+p][k] ----------------
__global__ __launch_bounds__(256) void k_tmm(const u16* __restrict__ thT,
    const u16* __restrict__ X, u16* __restrict__ tT){
  __shared__ __align__(16) u16 As[128*64];
  __shared__ __align__(16) u16 Bs[128*64];
  const int g = blockIdx.x, h = blockIdx.y;
  const int tid = threadIdx.x, l = tid & 63, wid = tid >> 6;
  const int wr = wid >> 1, wc = wid & 1, lm = l & 15, lk = l >> 4;
  f32x4 acc[4][4] = {};
  for (int kt = 0; kt < 4; ++kt){
    if (kt) __syncthreads();
    stage64(thT, (size_t)h*128, D_, kt*64, As, tid);
    stage64(X,   (size_t)g*128, D_, kt*64, Bs, tid);
    __syncthreads();
    #pragma unroll
    for (int ks = 0; ks < 2; ++ks){
      bf16x8 a[4], b[4];
      #pragma unroll
      for (int mi = 0; mi < 4; ++mi) a[mi] = ldf(As, wr*64 + mi*16 + lm, ks*4 + lk, 8);
      #pragma unroll
      for (int ni = 0; ni < 4; ++ni) b[ni] = ldf(Bs, wc*64 + ni*16 + lm, ks*4 + lk, 8);
      #pragma unroll
      for (int mi = 0; mi < 4; ++mi)
        #pragma unroll
        for (int ni = 0; ni < 4; ++ni)
          acc[mi][ni] = __builtin_amdgcn_mfma_f32_16x16x32_bf16(a[mi], b[ni], acc[mi][ni], 0, 0, 0);
    }
  }
  #pragma unroll
  for (int mi = 0; mi < 4; ++mi)
    #pragma unroll
    for (int ni = 0; ni < 4; ++ni)
      #pragma unroll
      for (int r = 0; r < 4; ++r){
        const int row = wr*64 + mi*16 + lk*4 + r;   // n within half
        const int col = wc*64 + ni*16 + lm;         // p
        tT[((size_t)g*D_ + h*128 + row)*PB_ + col] = f2bf(acc[mi][ni][r]);
      }
}

// ---------------- big GEMM: o[token][512] = X @ [wt|wh]^T ----------------
__global__ __launch_bounds__(256) void k_gg(const u16* __restrict__ X,
    const u16* __restrict__ WT, u16* __restrict__ o){
  __shared__ __align__(16) u16 As[128*64];
  __shared__ __align__(16) u16 Bs[128*64];
  const int n0 = blockIdx.x * 128;
  const size_t r0 = (size_t)blockIdx.y * 128;
  const int tid = threadIdx.x, l = tid & 63, wid = tid >> 6;
  const int wr = wid >> 1, wc = wid & 1, lm = l & 15, lk = l >> 4;
  f32x4 acc[4][4] = {};
  for (int kt = 0; kt < 4; ++kt){
    if (kt) __syncthreads();
    stage64(X,  r0,          D_, kt*64, As, tid);
    stage64(WT, (size_t)n0,  D_, kt*64, Bs, tid);
    __syncthreads();
    #pragma unroll
    for (int ks = 0; ks < 2; ++ks){
      bf16x8 a[4], b[4];
      #pragma unroll
      for (int mi = 0; mi < 4; ++mi) a[mi] = ldf(As, wr*64 + mi*16 + lm, ks*4 + lk, 8);
      #pragma unroll
      for (int ni = 0; ni < 4; ++ni) b[ni] = ldf(Bs, wc*64 + ni*16 + lm, ks*4 + lk, 8);
      #pragma unroll
      for (int mi = 0; mi < 4; ++mi)
        #pragma unroll
        for (int ni = 0; ni < 4; ++ni)
          acc[mi][ni] = __builtin_amdgcn_mfma_f32_16x16x32_bf16(a[mi], b[ni], acc[mi][ni], 0, 0, 0);
    }
  }
  #pragma unroll
  for (int mi = 0; mi < 4; ++mi)
    #pragma unroll
    for (int ni = 0; ni < 4; ++ni)
      #pragma unroll
      for (int r = 0; r < 4; ++r){
        const int row = wr*64 + mi*16 + lk*4 + r;
        const int col = wc*64 + ni*16 + lm;
        o[(r0 + row)*512 + n0 + col] = f2bf(acc[mi][ni][r]);
      }
}

// ---------------- fused per-bin GEMM (dm @ tT) + gate/het mix epilogue ----------------
template<int OUT>   // 0: write bf16 [token][256]; 1: scatter fp32 to out
__global__ __launch_bounds__(256) void k_bmix(const u16* __restrict__ dmb,
    const u16* __restrict__ tT, const u16* __restrict__ atah,
    const float* __restrict__ btv, const int* __restrict__ split,
    u16* __restrict__ o16, float* __restrict__ o32){
  __shared__ __align__(16) u16 As[128*128];
  __shared__ __align__(16) u16 Bs[128*128];
  __shared__ int ssp[128];
  const int h = blockIdx.x, g = blockIdx.y;
  const int tid = threadIdx.x, l = tid & 63, wid = tid >> 6;
  const int wr = wid >> 1, wc = wid & 1, lm = l & 15, lk = l >> 4;
  stage128(dmb, (size_t)g*128, PB_, As, tid);
  stage128(tT, (size_t)g*D_ + h*128, PB_, Bs, tid);
  if (OUT){ if (tid < 128) ssp[tid] = split[g*128 + tid]; }
  __syncthreads();
  f32x4 acc[4][4] = {};
  #pragma unroll
  for (int ks = 0; ks < 4; ++ks){
    bf16x8 a[4], b[4];
    #pragma unroll
    for (int mi = 0; mi < 4; ++mi) a[mi] = ldf(As, wr*64 + mi*16 + lm, ks*4 + lk, 16);
    #pragma unroll
    for (int ni = 0; ni < 4; ++ni) b[ni] = ldf(Bs, wc*64 + ni*16 + lm, ks*4 + lk, 16);
    #pragma unroll
    for (int mi = 0; mi < 4; ++mi)
      #pragma unroll
      for (int ni = 0; ni < 4; ++ni)
        acc[mi][ni] = __builtin_amdgcn_mfma_f32_16x16x32_bf16(a[mi], b[ni], acc[mi][ni], 0, 0, 0);
  }
  __syncthreads();
  // restage at/ah tiles (linear LDS, coalesced global reads)
  #pragma unroll
  for (int s = 0; s < 8; ++s){
    const int r = (tid >> 4) + s*16, c8 = tid & 15;
    const size_t gbase = ((size_t)g*128 + r)*512 + h*128 + c8*8;
    *(bf16x8*)&As[r*128 + c8*8] = *(const bf16x8*)&atah[gbase];
    *(bf16x8*)&Bs[r*128 + c8*8] = *(const bf16x8*)&atah[gbase + 256];
  }
  __syncthreads();
  #pragma unroll
  for (int mi = 0; mi < 4; ++mi)
    #pragma unroll
    for (int ni = 0; ni < 4; ++ni){
      const int colc = wc*64 + ni*16 + lm;
      const int gc = h*128 + colc;
      const float bb = btv[gc];
      #pragma unroll
      for (int r = 0; r < 4; ++r){
        const int row = wr*64 + mi*16 + lk*4 + r;
        const float at = bf2f(As[row*128 + colc]);
        const float ahv = bf2f(Bs[row*128 + colc]);
        const float gt = 1.f/(1.f + expf(-(at + bb)));
        const float o = eluf(gt*acc[mi][ni][r] + (1.f - gt)*ahv);
        if (OUT == 0){
          o16[((size_t)g*128 + row)*D_ + gc] = f2bf(o);
        } else {
          const int b = g / NBINS_;
          o32[((size_t)b*NP_ + ssp[row])*D_ + gc] = o;
        }
      }
    }
}

// ---------------- driver ----------------
extern "C" void kernel_launch(void* const* d_in, const int* in_sizes, int n_in,
                              void* d_out, int out_size, void* d_ws, size_t ws_size,
                              hipStream_t stream){
  (void)in_sizes; (void)n_in; (void)out_size;
  const float* x    = (const float*)d_in[0];
  const void*  msk  = d_in[1];
  const float* ln_g = (const float*)d_in[2];
  const float* ln_b = (const float*)d_in[3];
  const float* w1 = (const float*)d_in[4];
  const float* b1 = (const float*)d_in[5];
  const float* w2 = (const float*)d_in[6];
  const float* b2 = (const float*)d_in[7];
  const float* w3 = (const float*)d_in[8];
  const float* b3 = (const float*)d_in[9];
  const float* cb = (const float*)d_in[10];
  const float* th0 = (const float*)d_in[11];
  const float* wh0 = (const float*)d_in[12];
  const float* wt0 = (const float*)d_in[13];
  const float* bt0 = (const float*)d_in[14];
  const float* th1 = (const float*)d_in[15];
  const float* wh1 = (const float*)d_in[16];
  const float* wt1 = (const float*)d_in[17];
  const float* bt1 = (const float*)d_in[18];
  float* out = (float*)d_out;

  char* ws = (char*)d_ws;
  size_t off = 0;
  auto alloc = [&](size_t bytes) -> void* {
    void* p = ws + off; off += (bytes + 255) & ~(size_t)255; return p;
  };
  int* flags = (int*)alloc(2*sizeof(int));
  int* hist  = (int*)alloc((size_t)B_*NIDS_*4);
  int* offs  = (int*)alloc((size_t)B_*NIDS_*4);
  int* bidx  = (int*)alloc((size_t)T_*4);
  int* split = (int*)alloc((size_t)T_*4);
  float* mskf = (float*)alloc((size_t)T_*4);
  float* mskg = (float*)alloc((size_t)T_*4);
  u16* thT0 = (u16*)alloc((size_t)D_*D_*2);
  u16* thT1 = (u16*)alloc((size_t)D_*D_*2);
  u16* wtwh0 = (u16*)alloc((size_t)512*D_*2);
  u16* wtwh1 = (u16*)alloc((size_t)512*D_*2);
  // BIG0: FFN intermediates P|Q (fp32, T*128 each) -> later atah (u16 T*512)
  char* regA = (char*)alloc((size_t)T_*512*2);
  // BIG1..BIG4
  u16* xmh = (u16*)alloc((size_t)T_*D_*2);
  char* regC = (char*)alloc((size_t)T_*D_*2);   // xkh | dmb
  u16* tT  = (u16*)alloc((size_t)T_*D_*2);
  u16* xb1 = (u16*)alloc((size_t)T_*D_*2);
  if (off > ws_size) return;  // insufficient workspace: leave poison (visible failure)

  float* P = (float*)regA;
  float* Q = P + (size_t)T_*DD_;
  u16* atah = (u16*)regA;
  u16* xkh = (u16*)regC;
  u16* dmb = xkh + (size_t)T_*DD_;
  float* xn = out;            // d_out holds xn until the final k_bmix<1> scatter

  hipMemsetAsync(flags, 0, 2*sizeof(int), stream);
  hipMemsetAsync(hist, 0, (size_t)B_*NIDS_*4, stream);

  k_mask_detect<<<64, 256, 0, stream>>>((const unsigned int*)msk, flags);
  k_mask_convert<<<T_/256, 256, 0, stream>>>(msk, flags, mskf);

  k_ln<<<T_/4, 256, 0, stream>>>(x, ln_g, ln_b, xn);

  k_wt<<<256, 256, 0, stream>>>(th0, thT0);
  k_wt<<<256, 256, 0, stream>>>(th1, thT1);
  k_wt2<<<512, 256, 0, stream>>>(wt0, wh0, wtwh0);
  k_wt2<<<512, 256, 0, stream>>>(wt1, wh1, wtwh1);

  // FFN (exact fp32 — bit-identical to round 2 so LSH bins match)
  k_gemm<D_, H_, 1><<<dim3(T_/64, H_/64), 256, 0, stream>>>(xn, w1, b1, P);
  k_gemm<H_, H_, 1><<<dim3(T_/64, H_/64), 256, 0, stream>>>(P, w2, b2, Q);
  k_gemm<H_, DD_, 1><<<dim3(T_/64, DD_/64), 256, 0, stream>>>(Q, w3, b3, P);

  k_lsh<<<T_/16, 256, 0, stream>>>(P, cb, mskf, bidx);
  k_hist<<<T_/256, 256, 0, stream>>>(bidx, hist);
  k_prefix<<<1, 64, 0, stream>>>(hist, offs);
  k_binsort<<<B_*NIDS_, 64, 0, stream>>>(bidx, offs, hist, split);

  k_gather<<<T_, 256, 0, stream>>>(xn, P, mskf, split, xmh, xkh, mskg);
  k_dm<<<GT_, 256, 0, stream>>>(xkh, mskg, dmb);

  // layer 0 (atah overwrites P/Q region — P dead after k_gather)
  k_gg<<<dim3(4, T_/128), 256, 0, stream>>>(xmh, wtwh0, atah);
  k_tmm<<<dim3(GT_, 2), 256, 0, stream>>>(thT0, xmh, tT);
  k_bmix<0><<<dim3(2, GT_), 256, 0, stream>>>(dmb, tT, atah, bt0, nullptr, xb1, nullptr);

  // layer 1 (writes final output scattered via split)
  k_gg<<<dim3(4, T_/128), 256, 0, stream>>>(xb1, wtwh1, atah);
  k_tmm<<<dim3(GT_, 2), 256, 0, stream>>>(thT1, xb1, tT);
  k_bmix<1><<<dim3(2, GT_), 256, 0, stream>>>(dmb, tT, atah, bt1, split, nullptr, out);
}

// Round 5
// 1523.940 us; speedup vs baseline: 3.4923x; 1.2719x over previous
//
#include <hip/hip_runtime.h>
#include <math.h>

#define B_ 8
#define NP_ 25600
#define T_ (B_*NP_)          // 204800 tokens
#define D_ 256
#define H_ 128
#define DD_ 128
#define NBINS_ 200
#define NIDS_ 400            // bin_idx in [0, 398]
#define PB_ 128              // bin size
#define NC_ 100              // codebook columns used
#define GT_ (B_*NBINS_)      // 1600 bins total

typedef __attribute__((ext_vector_type(8))) short bf16x8;
typedef __attribute__((ext_vector_type(4))) float f32x4;
typedef __attribute__((ext_vector_type(4))) unsigned short u16x4;
typedef unsigned short u16;

__device__ __forceinline__ float eluf(float v){ return v > 0.f ? v : expm1f(v); }
__device__ __forceinline__ u16 f2bf(float f){
  union { float f; unsigned u; } v; v.f = f;
  unsigned r = v.u + 0x7fffu + ((v.u >> 16) & 1u);
  return (u16)(r >> 16);
}
__device__ __forceinline__ float bf2f(u16 h){
  union { unsigned u; float f; } v; v.u = ((unsigned)h) << 16; return v.f;
}

// ---------------- mask dtype detection & conversion ----------------
__global__ void k_mask_detect(const unsigned int* __restrict__ m, int* __restrict__ flags){
  int any_f1 = 0, any_o = 0;
  for (int i = blockIdx.x*blockDim.x + threadIdx.x; i < T_/4; i += gridDim.x*blockDim.x){
    unsigned int w = m[i];
    if (w == 0x3F800000u) any_f1 = 1;
    else if (w > 1u) any_o = 1;
  }
  if (any_f1) atomicOr(&flags[0], 1);
  if (any_o)  atomicOr(&flags[1], 1);
}

__global__ void k_mask_convert(const void* __restrict__ m, const int* __restrict__ flags,
                               float* __restrict__ mskf){
  int i = blockIdx.x*256 + threadIdx.x;
  int mode = flags[0] ? 2 : (flags[1] ? 1 : 0);  // 2=f32, 1=u8, 0=i32
  bool v;
  if (mode == 2)      v = ((const float*)m)[i] != 0.f;
  else if (mode == 1) v = ((const unsigned char*)m)[i] != 0;
  else                v = ((const int*)m)[i] != 0;
  mskf[i] = v ? 1.f : 0.f;
}

// ---------------- layernorm: one wave per token ----------------
__global__ __launch_bounds__(256) void k_ln(const float* __restrict__ x,
    const float* __restrict__ g, const float* __restrict__ b, float* __restrict__ xn){
  const int wave = threadIdx.x >> 6, lane = threadIdx.x & 63;
  const long t = (long)blockIdx.x*4 + wave;
  float4 v = ((const float4*)(x + t*D_))[lane];
  float s  = v.x + v.y + v.z + v.w;
  float s2 = v.x*v.x + v.y*v.y + v.z*v.z + v.w*v.w;
  #pragma unroll
  for (int o = 32; o; o >>= 1){ s += __shfl_xor(s, o); s2 += __shfl_xor(s2, o); }
  const float mu = s * (1.f/D_);
  float var = s2*(1.f/D_) - mu*mu;
  var = fmaxf(var, 0.f);
  const float rs = rsqrtf(var + 1e-6f);
  float4 gg = ((const float4*)g)[lane];
  float4 bb = ((const float4*)b)[lane];
  float4 o4;
  o4.x = (v.x-mu)*rs*gg.x + bb.x;
  o4.y = (v.y-mu)*rs*gg.y + bb.y;
  o4.z = (v.z-mu)*rs*gg.z + bb.z;
  o4.w = (v.w-mu)*rs*gg.w + bb.w;
  ((float4*)(xn + t*D_))[lane] = o4;
}

// ---------------- fp32 FFN GEMM: 128x128 tile, K-chunk 32, 8x8 microtile ----------------
// Bit-identical to the round-2/4 k_gemm: each acc is an fmaf chain over k ascending
// with identical fp32 operands. N fixed at 128. Epilogue: bias + elu.
template<int K>
__global__ __launch_bounds__(256) void k_gemm2(const float* __restrict__ A,
    const float* __restrict__ W, const float* __restrict__ bias, float* __restrict__ C){
  __shared__ __align__(16) float As[32*132];   // [k][m]
  __shared__ __align__(16) float Bs[32*132];   // [k][n]
  const size_t m0 = (size_t)blockIdx.x * 128;
  const int tid = threadIdx.x;
  const int tm = tid >> 4, tn = tid & 15;
  float acc[8][8] = {};
  for (int kc = 0; kc < K; kc += 32){
    __syncthreads();
    {
      const int r = tid >> 1, kq = (tid & 1) * 16;
      const float* src = &A[(m0 + r)*(size_t)K + kc + kq];
      #pragma unroll
      for (int q = 0; q < 4; ++q){
        const float4 v = ((const float4*)src)[q];
        As[(kq + q*4 + 0)*132 + r] = v.x;
        As[(kq + q*4 + 1)*132 + r] = v.y;
        As[(kq + q*4 + 2)*132 + r] = v.z;
        As[(kq + q*4 + 3)*132 + r] = v.w;
      }
      const int kk = tid >> 3, n0 = (tid & 7) * 16;
      const float* wsrc = &W[(size_t)(kc + kk)*128 + n0];
      #pragma unroll
      for (int q = 0; q < 4; ++q)
        *(float4*)&Bs[kk*132 + n0 + q*4] = ((const float4*)wsrc)[q];
    }
    __syncthreads();
    #pragma unroll
    for (int k = 0; k < 32; ++k){
      float a[8], b[8];
      *(float4*)&a[0] = *(const float4*)&As[k*132 + tm*8];
      *(float4*)&a[4] = *(const float4*)&As[k*132 + tm*8 + 4];
      *(float4*)&b[0] = *(const float4*)&Bs[k*132 + tn*8];
      *(float4*)&b[4] = *(const float4*)&Bs[k*132 + tn*8 + 4];
      #pragma unroll
      for (int i = 0; i < 8; ++i)
        #pragma unroll
        for (int j = 0; j < 8; ++j)
          acc[i][j] = fmaf(a[i], b[j], acc[i][j]);
    }
  }
  #pragma unroll
  for (int i = 0; i < 8; ++i){
    const size_t row = m0 + tm*8 + i;
    #pragma unroll
    for (int q = 0; q < 2; ++q){
      float4 o;
      o.x = eluf(acc[i][q*4+0] + bias[tn*8 + q*4+0]);
      o.y = eluf(acc[i][q*4+1] + bias[tn*8 + q*4+1]);
      o.z = eluf(acc[i][q*4+2] + bias[tn*8 + q*4+2]);
      o.w = eluf(acc[i][q*4+3] + bias[tn*8 + q*4+3]);
      *(float4*)&C[row*128 + tn*8 + q*4] = o;
    }
  }
}

// ---------------- codebook pad: cbp[128][128], cols >= 100 zero ----------------
__global__ void k_cbpad(const float* __restrict__ cb, float* __restrict__ cbp){
  const int k = blockIdx.x, c = threadIdx.x;   // 128 x 128
  cbp[k*128 + c] = (c < NC_) ? cb[k*NC_ + c] : 0.f;
}

// ---------------- fused mul GEMM + argmax (bit-identical bins vs k_lsh) ----------------
__global__ __launch_bounds__(256) void k_mulmax(const float* __restrict__ A,
    const float* __restrict__ CB, const float* __restrict__ mskf, int* __restrict__ bidx){
  __shared__ __align__(16) float As[32*132];
  __shared__ __align__(16) float Bs[32*132];
  const size_t m0 = (size_t)blockIdx.x * 128;
  const int tid = threadIdx.x;
  const int tm = tid >> 4, tn = tid & 15;
  float acc[8][8] = {};
  for (int kc = 0; kc < DD_; kc += 32){
    __syncthreads();
    {
      const int r = tid >> 1, kq = (tid & 1) * 16;
      const float* src = &A[(m0 + r)*(size_t)DD_ + kc + kq];
      #pragma unroll
      for (int q = 0; q < 4; ++q){
        const float4 v = ((const float4*)src)[q];
        As[(kq + q*4 + 0)*132 + r] = v.x;
        As[(kq + q*4 + 1)*132 + r] = v.y;
        As[(kq + q*4 + 2)*132 + r] = v.z;
        As[(kq + q*4 + 3)*132 + r] = v.w;
      }
      const int kk = tid >> 3, n0 = (tid & 7) * 16;
      const float* wsrc = &CB[(size_t)(kc + kk)*128 + n0];
      #pragma unroll
      for (int q = 0; q < 4; ++q)
        *(float4*)&Bs[kk*132 + n0 + q*4] = ((const float4*)wsrc)[q];
    }
    __syncthreads();
    #pragma unroll
    for (int k = 0; k < 32; ++k){
      float a[8], b[8];
      *(float4*)&a[0] = *(const float4*)&As[k*132 + tm*8];
      *(float4*)&a[4] = *(const float4*)&As[k*132 + tm*8 + 4];
      *(float4*)&b[0] = *(const float4*)&Bs[k*132 + tn*8];
      *(float4*)&b[4] = *(const float4*)&Bs[k*132 + tn*8 + 4];
      #pragma unroll
      for (int i = 0; i < 8; ++i)
        #pragma unroll
        for (int j = 0; j < 8; ++j)
          acc[i][j] = fmaf(a[i], b[j], acc[i][j]);
    }
  }
  // per-row argmax over [mul, -mul]: max value, smallest index on ties
  #pragma unroll
  for (int i = 0; i < 8; ++i){
    float bv = -1e30f; int bi = 0;
    #pragma unroll
    for (int j = 0; j < 8; ++j){
      const int c = tn*8 + j;
      if (c < NC_){
        const float v = acc[i][j];
        if (v > bv || (v == bv && c < bi)){ bv = v; bi = c; }
        const float nv = -v; const int nc2 = c + NC_;
        if (nv > bv || (nv == bv && nc2 < bi)){ bv = nv; bi = nc2; }
      }
    }
    #pragma unroll
    for (int o = 1; o < 16; o <<= 1){
      const float ov = __shfl_xor(bv, o);
      const int oi = __shfl_xor(bi, o);
      if (ov > bv || (ov == bv && oi < bi)){ bv = ov; bi = oi; }
    }
    if (tn == 0){
      const size_t t = m0 + tm*8 + i;
      bidx[t] = bi + (mskf[t] != 0.f ? 0 : NBINS_ - 1);
    }
  }
}

// ---------------- counting sort (stable) ----------------
__global__ void k_hist(const int* __restrict__ bidx, int* __restrict__ hist){
  const int i = blockIdx.x*256 + threadIdx.x;
  const int b = i / NP_;
  atomicAdd(&hist[b*NIDS_ + bidx[i]], 1);
}

__global__ void k_prefix(const int* __restrict__ hist, int* __restrict__ offs){
  const int b = threadIdx.x;
  if (b < B_){
    int run = 0;
    for (int v = 0; v < NIDS_; ++v){ offs[b*NIDS_ + v] = run; run += hist[b*NIDS_ + v]; }
  }
}

__global__ __launch_bounds__(64) void k_binsort(const int* __restrict__ bidx,
    const int* __restrict__ offs, const int* __restrict__ hist, int* __restrict__ split){
  const int bv = blockIdx.x;            // b*NIDS_ + v
  if (hist[bv] == 0) return;
  const int b = bv / NIDS_, v = bv % NIDS_;
  int base = offs[bv];
  const int lane = threadIdx.x;
  const int* row = bidx + b*NP_;
  for (int i0 = 0; i0 < NP_; i0 += 64){
    const int i = i0 + lane;
    const bool m = (row[i] == v);
    const unsigned long long mk = __ballot(m);
    if (m){
      const int pos = base + __popcll(mk & ((1ull << lane) - 1ull));
      split[b*NP_ + pos] = i;
    }
    base += __popcll(mk);
  }
}

// ---------------- gather (fp32 -> masked bf16), wave per token ----------------
__global__ __launch_bounds__(256) void k_gather(const float* __restrict__ xn,
    const float* __restrict__ xd, const float* __restrict__ mskf,
    const int* __restrict__ split, u16* __restrict__ xmh,
    u16* __restrict__ xkh, float* __restrict__ mskg){
  const long j = (long)blockIdx.x*4 + (threadIdx.x >> 6);
  const int lane = threadIdx.x & 63;
  const int b = (int)(j / NP_);
  const int i = split[j];
  const long src = (long)b*NP_ + i;
  const float mv = mskf[src];
  const float4 v = ((const float4*)(xn + src*D_))[lane];
  u16x4 o;
  o[0] = f2bf(v.x*mv); o[1] = f2bf(v.y*mv); o[2] = f2bf(v.z*mv); o[3] = f2bf(v.w*mv);
  ((u16x4*)(xmh + j*D_))[lane] = o;
  if (lane < 32){
    const float4 w = ((const float4*)(xd + src*DD_))[lane];
    u16x4 ow;
    ow[0] = f2bf(w.x*mv); ow[1] = f2bf(w.y*mv); ow[2] = f2bf(w.z*mv); ow[3] = f2bf(w.w*mv);
    ((u16x4*)(xkh + j*DD_))[lane] = ow;
  }
  if (lane == 0) mskg[j] = mv;
}

// ---------------- weight prep ----------------
__global__ __launch_bounds__(256) void k_wt(const float* __restrict__ W, u16* __restrict__ o){
  const int n = blockIdx.x, k = threadIdx.x;
  o[n*D_ + k] = f2bf(W[k*D_ + n]);
}
__global__ __launch_bounds__(256) void k_wt2(const float* __restrict__ wt,
    const float* __restrict__ wh, u16* __restrict__ o){
  const int n = blockIdx.x, k = threadIdx.x;   // grid 512, thr 256
  const float v = (n < 256) ? wt[(size_t)k*D_ + n] : wh[(size_t)k*D_ + (n-256)];
  o[(size_t)n*D_ + k] = f2bf(v);
}

// ---------------- MFMA LDS helpers (XOR swizzle at 16B granularity) ----------------
__device__ __forceinline__ void stage64(const u16* __restrict__ g, size_t row0,
    int ld, int k0, u16* Ls, int tid){
  #pragma unroll
  for (int s = 0; s < 4; ++s){
    const int r = (tid >> 3) + s*32, c8 = tid & 7;
    bf16x8 v = *(const bf16x8*)&g[(row0 + r)*(size_t)ld + k0 + c8*8];
    *(bf16x8*)&Ls[(r*8 + (c8 ^ (r & 7)))*8] = v;
  }
}
__device__ __forceinline__ void stage128(const u16* __restrict__ g, size_t row0,
    int ld, u16* Ls, int tid){
  #pragma unroll
  for (int s = 0; s < 8; ++s){
    const int r = (tid >> 4) + s*16, c8 = tid & 15;
    bf16x8 v = *(const bf16x8*)&g[(row0 + r)*(size_t)ld + c8*8];
    *(bf16x8*)&Ls[(r*16 + (c8 ^ (r & 7)))*8] = v;
  }
}
__device__ __forceinline__ bf16x8 ldf(const u16* Ls, int row, int c8, int ldc8){
  return *(const bf16x8*)&Ls[(row*ldc8 + (c8 ^ (row & 7)))*8];
}

// ---------------- per-bin Gram + Gaussian kernel matrix (MFMA) ----------------
__global__ __launch_bounds__(256) void k_dm(const u16* __restrict__ xk,
    const float* __restrict__ rm, u16* __restrict__ dmb){
  __shared__ __align__(16) u16 Xs[128*128];
  __shared__ float nsq[128];
  __shared__ float msl[128];
  const int g = blockIdx.x;
  const int tid = threadIdx.x, l = tid & 63, wid = tid >> 6;
  const int wr = wid >> 1, wc = wid & 1, lm = l & 15, lk = l >> 4;
  stage128(xk, (size_t)g*128, DD_, Xs, tid);
  if (tid < 128) msl[tid] = rm[(size_t)g*128 + tid];
  __syncthreads();
  f32x4 acc[4][4] = {};
  #pragma unroll
  for (int ks = 0; ks < 4; ++ks){
    bf16x8 a[4], b[4];
    #pragma unroll
    for (int mi = 0; mi < 4; ++mi) a[mi] = ldf(Xs, wr*64 + mi*16 + lm, ks*4 + lk, 16);
    #pragma unroll
    for (int ni = 0; ni < 4; ++ni) b[ni] = ldf(Xs, wc*64 + ni*16 + lm, ks*4 + lk, 16);
    #pragma unroll
    for (int mi = 0; mi < 4; ++mi)
      #pragma unroll
      for (int ni = 0; ni < 4; ++ni)
        acc[mi][ni] = __builtin_amdgcn_mfma_f32_16x16x32_bf16(a[mi], b[ni], acc[mi][ni], 0, 0, 0);
  }
  if (wr == wc && ((lm >> 2) == lk)){
    #pragma unroll
    for (int mi = 0; mi < 4; ++mi)
      nsq[wr*64 + mi*16 + lm] = acc[mi][mi][lm & 3];
  }
  __syncthreads();
  #pragma unroll
  for (int mi = 0; mi < 4; ++mi)
    #pragma unroll
    for (int ni = 0; ni < 4; ++ni)
      #pragma unroll
      for (int r = 0; r < 4; ++r){
        const int row = wr*64 + mi*16 + lk*4 + r;
        const int col = wc*64 + ni*16 + lm;
        float d2 = nsq[row] + nsq[col] - 2.f*acc[mi][ni][r];
        d2 = fminf(fmaxf(d2, 1e-6f), 1e6f);
        float w = expf(-0.1f * sqrtf(d2));
        w = fminf(w, 1.f);
        dmb[((size_t)g*PB_ + row)*PB_ + col] = f2bf(w * msl[row] * msl[col]);
      }
}

// ---------------- tT[g][n][p] = sum_k thT[n][k] * X[g*128+p][k] ----------------
__global__ __launch_bounds__(256) void k_tmm(const u16* __restrict__ thT,
    const u16* __restrict__ X, u16* __restrict__ tT){
  __shared__ __align__(16) u16 As[128*64];
  __shared__ __align__(16) u16 Bs[128*64];
  const int g = blockIdx.x, h = blockIdx.y;
  const int tid = threadIdx.x, l = tid & 63, wid = tid >> 6;
  const int wr = wid >> 1, wc = wid & 1, lm = l & 15, lk = l >> 4;
  f32x4 acc[4][4] = {};
  for (int kt = 0; kt < 4; ++kt){
    if (kt) __syncthreads();
    stage64(thT, (size_t)h*128, D_, kt*64, As, tid);
    stage64(X,   (size_t)g*128, D_, kt*64, Bs, tid);
    __syncthreads();
    #pragma unroll
    for (int ks = 0; ks < 2; ++ks){
      bf16x8 a[4], b[4];
      #pragma unroll
      for (int mi = 0; mi < 4; ++mi) a[mi] = ldf(As, wr*64 + mi*16 + lm, ks*4 + lk, 8);
      #pragma unroll
      for (int ni = 0; ni < 4; ++ni) b[ni] = ldf(Bs, wc*64 + ni*16 + lm, ks*4 + lk, 8);
      #pragma unroll
      for (int mi = 0; mi < 4; ++mi)
        #pragma unroll
        for (int ni = 0; ni < 4; ++ni)
          acc[mi][ni] = __builtin_amdgcn_mfma_f32_16x16x32_bf16(a[mi], b[ni], acc[mi][ni], 0, 0, 0);
    }
  }
  #pragma unroll
  for (int mi = 0; mi < 4; ++mi)
    #pragma unroll
    for (int ni = 0; ni < 4; ++ni)
      #pragma unroll
      for (int r = 0; r < 4; ++r){
        const int row = wr*64 + mi*16 + lk*4 + r;   // n within half
        const int col = wc*64 + ni*16 + lm;         // p
        tT[((size_t)g*D_ + h*128 + row)*PB_ + col] = f2bf(acc[mi][ni][r]);
      }
}

// ---------------- big GEMM: o[token][512] = X @ [wt|wh]^T ----------------
__global__ __launch_bounds__(256) void k_gg(const u16* __restrict__ X,
    const u16* __restrict__ WT, u16* __restrict__ o){
  __shared__ __align__(16) u16 As[128*64];
  __shared__ __align__(16) u16 Bs[128*64];
  const int n0 = blockIdx.x * 128;
  const size_t r0 = (size_t)blockIdx.y * 128;
  const int tid = threadIdx.x, l = tid & 63, wid = tid >> 6;
  const int wr = wid >> 1, wc = wid & 1, lm = l & 15, lk = l >> 4;
  f32x4 acc[4][4] = {};
  for (int kt = 0; kt < 4; ++kt){
    if (kt) __syncthreads();
    stage64(X,  r0,          D_, kt*64, As, tid);
    stage64(WT, (size_t)n0,  D_, kt*64, Bs, tid);
    __syncthreads();
    #pragma unroll
    for (int ks = 0; ks < 2; ++ks){
      bf16x8 a[4], b[4];
      #pragma unroll
      for (int mi = 0; mi < 4; ++mi) a[mi] = ldf(As, wr*64 + mi*16 + lm, ks*4 + lk, 8);
      #pragma unroll
      for (int ni = 0; ni < 4; ++ni) b[ni] = ldf(Bs, wc*64 + ni*16 + lm, ks*4 + lk, 8);
      #pragma unroll
      for (int mi = 0; mi < 4; ++mi)
        #pragma unroll
        for (int ni = 0; ni < 4; ++ni)
          acc[mi][ni] = __builtin_amdgcn_mfma_f32_16x16x32_bf16(a[mi], b[ni], acc[mi][ni], 0, 0, 0);
    }
  }
  #pragma unroll
  for (int mi = 0; mi < 4; ++mi)
    #pragma unroll
    for (int ni = 0; ni < 4; ++ni)
      #pragma unroll
      for (int r = 0; r < 4; ++r){
        const int row = wr*64 + mi*16 + lk*4 + r;
        const int col = wc*64 + ni*16 + lm;
        o[(r0 + row)*512 + n0 + col] = f2bf(acc[mi][ni][r]);
      }
}

// ---------------- fused per-bin GEMM (dm @ tT) + gate/het mix epilogue ----------------
template<int OUT>   // 0: write bf16 [token][256]; 1: scatter fp32 to out
__global__ __launch_bounds__(256) void k_bmix(const u16* __restrict__ dmb,
    const u16* __restrict__ tT, const u16* __restrict__ atah,
    const float* __restrict__ btv, const int* __restrict__ split,
    u16* __restrict__ o16, float* __restrict__ o32){
  __shared__ __align__(16) u16 As[128*128];
  __shared__ __align__(16) u16 Bs[128*128];
  __shared__ int ssp[128];
  const int h = blockIdx.x, g = blockIdx.y;
  const int tid = threadIdx.x, l = tid & 63, wid = tid >> 6;
  const int wr = wid >> 1, wc = wid & 1, lm = l & 15, lk = l >> 4;
  stage128(dmb, (size_t)g*128, PB_, As, tid);
  stage128(tT, (size_t)g*D_ + h*128, PB_, Bs, tid);
  if (OUT){ if (tid < 128) ssp[tid] = split[g*128 + tid]; }
  __syncthreads();
  f32x4 acc[4][4] = {};
  #pragma unroll
  for (int ks = 0; ks < 4; ++ks){
    bf16x8 a[4], b[4];
    #pragma unroll
    for (int mi = 0; mi < 4; ++mi) a[mi] = ldf(As, wr*64 + mi*16 + lm, ks*4 + lk, 16);
    #pragma unroll
    for (int ni = 0; ni < 4; ++ni) b[ni] = ldf(Bs, wc*64 + ni*16 + lm, ks*4 + lk, 16);
    #pragma unroll
    for (int mi = 0; mi < 4; ++mi)
      #pragma unroll
      for (int ni = 0; ni < 4; ++ni)
        acc[mi][ni] = __builtin_amdgcn_mfma_f32_16x16x32_bf16(a[mi], b[ni], acc[mi][ni], 0, 0, 0);
  }
  __syncthreads();
  // restage at/ah tiles (linear LDS, coalesced global reads)
  #pragma unroll
  for (int s = 0; s < 8; ++s){
    const int r = (tid >> 4) + s*16, c8 = tid & 15;
    const size_t gbase = ((size_t)g*128 + r)*512 + h*128 + c8*8;
    *(bf16x8*)&As[r*128 + c8*8] = *(const bf16x8*)&atah[gbase];
    *(bf16x8*)&Bs[r*128 + c8*8] = *(const bf16x8*)&atah[gbase + 256];
  }
  __syncthreads();
  #pragma unroll
  for (int mi = 0; mi < 4; ++mi)
    #pragma unroll
    for (int ni = 0; ni < 4; ++ni){
      const int colc = wc*64 + ni*16 + lm;
      const int gc = h*128 + colc;
      const float bb = btv[gc];
      #pragma unroll
      for (int r = 0; r < 4; ++r){
        const int row = wr*64 + mi*16 + lk*4 + r;
        const float at = bf2f(As[row*128 + colc]);
        const float ahv = bf2f(Bs[row*128 + colc]);
        const float gt = 1.f/(1.f + expf(-(at + bb)));
        const float o = eluf(gt*acc[mi][ni][r] + (1.f - gt)*ahv);
        if (OUT == 0){
          o16[((size_t)g*128 + row)*D_ + gc] = f2bf(o);
        } else {
          const int b = g / NBINS_;
          o32[((size_t)b*NP_ + ssp[row])*D_ + gc] = o;
        }
      }
    }
}

// ---------------- driver ----------------
extern "C" void kernel_launch(void* const* d_in, const int* in_sizes, int n_in,
                              void* d_out, int out_size, void* d_ws, size_t ws_size,
                              hipStream_t stream){
  (void)in_sizes; (void)n_in; (void)out_size;
  const float* x    = (const float*)d_in[0];
  const void*  msk  = d_in[1];
  const float* ln_g = (const float*)d_in[2];
  const float* ln_b = (const float*)d_in[3];
  const float* w1 = (const float*)d_in[4];
  const float* b1 = (const float*)d_in[5];
  const float* w2 = (const float*)d_in[6];
  const float* b2 = (const float*)d_in[7];
  const float* w3 = (const float*)d_in[8];
  const float* b3 = (const float*)d_in[9];
  const float* cb = (const float*)d_in[10];
  const float* th0 = (const float*)d_in[11];
  const float* wh0 = (const float*)d_in[12];
  const float* wt0 = (const float*)d_in[13];
  const float* bt0 = (const float*)d_in[14];
  const float* th1 = (const float*)d_in[15];
  const float* wh1 = (const float*)d_in[16];
  const float* wt1 = (const float*)d_in[17];
  const float* bt1 = (const float*)d_in[18];
  float* out = (float*)d_out;

  char* ws = (char*)d_ws;
  size_t off = 0;
  auto alloc = [&](size_t bytes) -> void* {
    void* p = ws + off; off += (bytes + 255) & ~(size_t)255; return p;
  };
  int* flags = (int*)alloc(2*sizeof(int));
  int* hist  = (int*)alloc((size_t)B_*NIDS_*4);
  int* offs  = (int*)alloc((size_t)B_*NIDS_*4);
  int* bidx  = (int*)alloc((size_t)T_*4);
  int* split = (int*)alloc((size_t)T_*4);
  float* mskf = (float*)alloc((size_t)T_*4);
  float* mskg = (float*)alloc((size_t)T_*4);
  float* cbp = (float*)alloc((size_t)128*128*4);
  u16* thT0 = (u16*)alloc((size_t)D_*D_*2);
  u16* thT1 = (u16*)alloc((size_t)D_*D_*2);
  u16* wtwh0 = (u16*)alloc((size_t)512*D_*2);
  u16* wtwh1 = (u16*)alloc((size_t)512*D_*2);
  // BIG0: FFN intermediates P|Q (fp32, T*128 each) -> later atah (u16 T*512)
  char* regA = (char*)alloc((size_t)T_*512*2);
  // BIG1..BIG4
  u16* xmh = (u16*)alloc((size_t)T_*D_*2);
  char* regC = (char*)alloc((size_t)T_*D_*2);   // xkh | dmb
  u16* tT  = (u16*)alloc((size_t)T_*D_*2);
  u16* xb1 = (u16*)alloc((size_t)T_*D_*2);
  if (off > ws_size) return;  // insufficient workspace: leave poison (visible failure)

  float* P = (float*)regA;
  float* Q = P + (size_t)T_*DD_;
  u16* atah = (u16*)regA;
  u16* xkh = (u16*)regC;
  u16* dmb = xkh + (size_t)T_*DD_;
  float* xn = out;            // d_out holds xn until the final k_bmix<1> scatter

  hipMemsetAsync(flags, 0, 2*sizeof(int), stream);
  hipMemsetAsync(hist, 0, (size_t)B_*NIDS_*4, stream);

  k_mask_detect<<<64, 256, 0, stream>>>((const unsigned int*)msk, flags);
  k_mask_convert<<<T_/256, 256, 0, stream>>>(msk, flags, mskf);

  k_ln<<<T_/4, 256, 0, stream>>>(x, ln_g, ln_b, xn);

  k_cbpad<<<128, 128, 0, stream>>>(cb, cbp);
  k_wt<<<256, 256, 0, stream>>>(th0, thT0);
  k_wt<<<256, 256, 0, stream>>>(th1, thT1);
  k_wt2<<<512, 256, 0, stream>>>(wt0, wh0, wtwh0);
  k_wt2<<<512, 256, 0, stream>>>(wt1, wh1, wtwh1);

  // FFN (exact fp32 — fmaf chain over ascending k, bit-identical to round 4)
  k_gemm2<D_><<<T_/128, 256, 0, stream>>>(xn, w1, b1, P);
  k_gemm2<H_><<<T_/128, 256, 0, stream>>>(P, w2, b2, Q);
  k_gemm2<H_><<<T_/128, 256, 0, stream>>>(Q, w3, b3, P);

  // LSH (fused mul GEMM + argmax; bins bit-identical to round 4's k_lsh)
  k_mulmax<<<T_/128, 256, 0, stream>>>(P, cbp, mskf, bidx);
  k_hist<<<T_/256, 256, 0, stream>>>(bidx, hist);
  k_prefix<<<1, 64, 0, stream>>>(hist, offs);
  k_binsort<<<B_*NIDS_, 64, 0, stream>>>(bidx, offs, hist, split);

  k_gather<<<T_/4, 256, 0, stream>>>(xn, P, mskf, split, xmh, xkh, mskg);
  k_dm<<<GT_, 256, 0, stream>>>(xkh, mskg, dmb);

  // layer 0 (atah overwrites P/Q region — P dead after k_gather)
  k_gg<<<dim3(4, T_/128), 256, 0, stream>>>(xmh, wtwh0, atah);
  k_tmm<<<dim3(GT_, 2), 256, 0, stream>>>(thT0, xmh, tT);
  k_bmix<0><<<dim3(2, GT_), 256, 0, stream>>>(dmb, tT, atah, bt0, nullptr, xb1, nullptr);

  // layer 1 (writes final output scattered via split)
  k_gg<<<dim3(4, T_/128), 256, 0, stream>>>(xb1, wtwh1, atah);
  k_tmm<<<dim3(GT_, 2), 256, 0, stream>>>(thT1, xb1, tT);
  k_bmix<1><<<dim3(2, GT_), 256, 0, stream>>>(dmb, tT, atah, bt1, split, nullptr, out);
}